// Round 3
// baseline (805.151 us; speedup 1.0000x reference)
//
#include <hip/hip_runtime.h>
#include <hip/hip_bf16.h>

#define EMBED 300
#define HD    128
#define LLEN  512
#define G4    512   // 4*H

// Workspace layout (floats):
#define OFF_LSTM 2097152
#define OFF_PROJ 2621440
#define OFF_MX   3145728
#define OFF_FEAT 3146752

typedef _Float16 half8 __attribute__((ext_vector_type(8)));
typedef float    f32x4 __attribute__((ext_vector_type(4)));

// ---------------- K1: embedding gather + X @ W_ih + b  → pre_g ----------------
__global__ __launch_bounds__(256) void k1_gemm(
    const int* __restrict__ qc, const int* __restrict__ ac,
    const float* __restrict__ emb, const float* __restrict__ wih,
    const float* __restrict__ bl, float* __restrict__ preg)
{
    __shared__ float As[32][65];
    __shared__ float Bs[32][64];
    const int m0 = blockIdx.x * 64;
    const int n0 = blockIdx.y * 64;
    const int tid = threadIdx.x;
    const int tx = tid & 15, ty = tid >> 4;
    float acc[4][4] = {};

    for (int k0 = 0; k0 < 300; k0 += 32) {
        #pragma unroll
        for (int i = 0; i < 8; ++i) {
            int e = tid + i * 256;
            int m = e >> 5, kk = e & 31;
            int row = m0 + m;
            int c = row >> 11, b = (row >> 9) & 3, t = row & 511;
            int tok = (c == 0 ? qc : ac)[b * LLEN + t];
            int k = k0 + kk;
            As[kk][m] = (k < 300) ? emb[(size_t)tok * EMBED + k] : 0.f;
        }
        #pragma unroll
        for (int i = 0; i < 8; ++i) {
            int e = tid + i * 256;
            int kk = e >> 6, n = e & 63;
            int k = k0 + kk;
            Bs[kk][n] = (k < 300) ? wih[k * G4 + n0 + n] : 0.f;
        }
        __syncthreads();
        #pragma unroll
        for (int kk = 0; kk < 32; ++kk) {
            float a[4], bv[4];
            #pragma unroll
            for (int i = 0; i < 4; ++i) a[i] = As[kk][ty * 4 + i];
            #pragma unroll
            for (int j = 0; j < 4; ++j) bv[j] = Bs[kk][tx * 4 + j];
            #pragma unroll
            for (int i = 0; i < 4; ++i)
                #pragma unroll
                for (int j = 0; j < 4; ++j)
                    acc[i][j] += a[i] * bv[j];
        }
        __syncthreads();
    }
    #pragma unroll
    for (int i = 0; i < 4; ++i) {
        int row = m0 + ty * 4 + i;
        #pragma unroll
        for (int j = 0; j < 4; ++j) {
            int n = n0 + tx * 4 + j;
            preg[(size_t)row * G4 + n] = acc[i][j] + bl[n];
        }
    }
}

// ---------------- K2: MFMA-batched LSTM scan. ONE workgroup, all 8 sequences ----------------
// D[m][n] per step: m = gate-col (512, tiled 16), n = seq slot (16, 8 active).
// A = Whh^T (static f16 frags in regs), B = h (f16, LDS), C-init = preg float4 loads.
__device__ __forceinline__ float fsig(float x) {
    return __fdividef(1.f, 1.f + __expf(-x));
}
__device__ __forceinline__ float ftanh(float x) {
    return 1.f - __fdividef(2.f, __expf(2.f * x) + 1.f);
}

__global__ __launch_bounds__(512, 1) void k2_lstm_mfma(
    const float* __restrict__ whh, const float* __restrict__ preg,
    float* __restrict__ lstm)
{
    const int tid = threadIdx.x;
    const int w  = tid >> 6;      // wave 0..7  -> units w*16..w*16+15
    const int l  = tid & 63;
    const int li = l & 15;        // A row / B col / D col index
    const int g  = l >> 4;        // lane group (k-block for A/B, row-block for D)

    __shared__ __align__(16) _Float16 hlds[16 * 136];  // [seq(16)][136] padded
    __shared__ float hout[8][132];                     // f32 h staging, padded

    // ---- static A fragments: A[m][k] = Whh[k][m_global], m_global = s*128 + w*16 + li
    half8 afrag[4][4];
    #pragma unroll
    for (int s = 0; s < 4; ++s) {
        const int mg = s * 128 + w * 16 + li;
        #pragma unroll
        for (int kt = 0; kt < 4; ++kt) {
            half8 v;
            #pragma unroll
            for (int e = 0; e < 8; ++e)
                v[e] = (_Float16)whh[(kt * 32 + g * 8 + e) * G4 + mg];
            afrag[kt][s] = v;  // [kt][s] indexing irrelevant; keep consistent below
        }
    }

    // zero h (only rows 0..7 matter; zero all to be safe)
    for (int i = tid; i < 16 * 136; i += 512) hlds[i] = (_Float16)0.f;

    const int seq = li;            // D column = sequence slot
    const bool act = seq < 8;
    const bool low = li < 8;

    // per-lane persistent cell state: 2 cells each
    // low lanes: (seq=li, units w*16+g*4+{0,1}); high lanes: (seq=li-8, units w*16+g*4+{2,3})
    float cA = 0.f, cB = 0.f;

    // pg (acc-init) pointers: float4 at preg[(seq*512+t)*512 + s*128 + w*16 + g*4]
    const f32x4* pg4 = (const f32x4*)(preg + (size_t)(seq & 7) * LLEN * G4);
    const int pgo = w * 4 + g;     // + s*32 + t*128

    f32x4 pgv[4];
    #pragma unroll
    for (int s = 0; s < 4; ++s) pgv[s] = act ? pg4[s * 32 + pgo] : (f32x4)(0.f);

    __syncthreads();

    #pragma unroll 1
    for (int t = 0; t < LLEN; ++t) {
        // B fragments: B[k][n] = h[seq=n][k]; inactive lanes duplicate partner row (broadcast)
        const _Float16* hp = hlds + (seq & 7) * 136;
        half8 bfrag[4];
        #pragma unroll
        for (int kt = 0; kt < 4; ++kt)
            bfrag[kt] = *(const half8*)(hp + kt * 32 + g * 8);

        // acc init from prefetched pre-gates
        f32x4 acc[4];
        #pragma unroll
        for (int s = 0; s < 4; ++s) acc[s] = pgv[s];

        // 16 MFMAs: acc[s] over 4 K-subtiles
        #pragma unroll
        for (int kt = 0; kt < 4; ++kt)
            #pragma unroll
            for (int s = 0; s < 4; ++s)
                acc[s] = __builtin_amdgcn_mfma_f32_16x16x32_f16(afrag[kt][s], bfrag[kt], acc[s], 0, 0, 0);

        // prefetch next step's pre-gates (hidden under nonlinearity)
        if (act && t + 1 < LLEN) {
            #pragma unroll
            for (int s = 0; s < 4; ++s) pgv[s] = pg4[(t + 1) * 128 + s * 32 + pgo];
        }

        // balance: send rows r=2,3 (acc[s][2],[3]) to partner lane l^8
        float r2[4], r3[4];
        #pragma unroll
        for (int s = 0; s < 4; ++s) {
            r2[s] = __shfl_xor(acc[s][2], 8, 64);
            r3[s] = __shfl_xor(acc[s][3], 8, 64);
        }
        // each lane: 2 cells
        float xiA = low ? acc[0][0] : r2[0];
        float xfA = low ? acc[1][0] : r2[1];
        float xgA = low ? acc[2][0] : r2[2];
        float xoA = low ? acc[3][0] : r2[3];
        float xiB = low ? acc[0][1] : r3[0];
        float xfB = low ? acc[1][1] : r3[1];
        float xgB = low ? acc[2][1] : r3[2];
        float xoB = low ? acc[3][1] : r3[3];

        float iA = fsig(xiA), fA = fsig(xfA), gA = ftanh(xgA), oA = fsig(xoA);
        cA = fA * cA + iA * gA;
        float hA = oA * ftanh(cA);

        float iB = fsig(xiB), fB = fsig(xfB), gB = ftanh(xgB), oB = fsig(xoB);
        cB = fB * cB + iB * gB;
        float hB = oB * ftanh(cB);

        __syncthreads();   // (A) all B-frag reads done before h rewrite

        const int sA = li & 7;
        const int uA = w * 16 + g * 4 + (low ? 0 : 2);
        // packed f16 write (uA even -> 4B aligned)
        union { _Float16 h2[2]; unsigned u32; } pk;
        pk.h2[0] = (_Float16)hA; pk.h2[1] = (_Float16)hB;
        *(unsigned*)(hlds + sA * 136 + uA) = pk.u32;
        *(float2*)&hout[sA][uA] = make_float2(hA, hB);

        __syncthreads();   // (B) h visible for next step + hout ready

        // coalesced global h write: thread covers (sq, u) and (sq+4, u)
        {
            const int sq = tid >> 7, u = tid & 127;
            lstm[((size_t)sq * LLEN + t) * HD + u]       = hout[sq][u];
            lstm[((size_t)(sq + 4) * LLEN + t) * HD + u] = hout[sq + 4][u];
        }
    }
}

// ---------------- K3: proj = lstm @ Wa_part (per side). 64 WGs ----------------
__global__ __launch_bounds__(512) void k3_proj(
    const float* __restrict__ wa, const float* __restrict__ lstm,
    float* __restrict__ proj)
{
    const int idx = blockIdx.x;
    const int tc = idx & 7, b = (idx >> 3) & 3, s = idx >> 5;
    __shared__ float wsm[128][128];
    const int tid = threadIdx.x;
    #pragma unroll
    for (int i = 0; i < 32; ++i) {
        int e = tid + i * 512;
        int k = e >> 7, h = e & 127;
        wsm[k][h] = wa[(s * 128 + k) * 128 + h];
    }
    __syncthreads();
    const float* lb = lstm + ((size_t)(s * 4 + b)) * LLEN * HD;
    float* pb = proj + ((size_t)(s * 4 + b)) * LLEN * HD;
    const int h = tid & 127, ts = tid >> 7;
    for (int i = 0; i < 16; ++i) {
        int t = tc * 64 + i * 4 + ts;
        const float* lr = lb + (size_t)t * HD;
        float acc = 0.f;
        #pragma unroll
        for (int k = 0; k < 128; ++k) acc += lr[k] * wsm[k][h];
        pb[(size_t)t * HD + h] = acc;
    }
}

// ---------------- K3b: per-(side,b,h) max over t ----------------
__global__ void k3_max(const float* __restrict__ proj, float* __restrict__ mx)
{
    const int cb = blockIdx.x;
    const int h = threadIdx.x;
    const float* p = proj + (size_t)cb * LLEN * HD;
    float m = -1e30f;
    #pragma unroll 8
    for (int t = 0; t < LLEN; ++t) m = fmaxf(m, p[(size_t)t * HD + h]);
    mx[cb * HD + h] = m;
}

// ---------------- K4: r (on the fly) + scores + softmax + feature ----------------
__global__ __launch_bounds__(512) void k4_attn(
    const float* __restrict__ lstm, const float* __restrict__ proj,
    const float* __restrict__ mx, const float* __restrict__ ba,
    const float* __restrict__ wq, const float* __restrict__ bq,
    const float* __restrict__ wans, const float* __restrict__ bans,
    float* __restrict__ feat)
{
    const int blk = blockIdx.x;
    const int s = blk >> 2, b = blk & 3;
    const float* wv = (s == 0) ? wq : wans;
    const float bias = (s == 0) ? bq[0] : bans[0];
    const float* lb = lstm + ((size_t)(s * 4 + b)) * LLEN * HD;
    const float* po = proj + ((size_t)((1 - s) * 4 + b)) * LLEN * HD;
    __shared__ float sl[512];
    __shared__ float red[512];
    __shared__ float bcast[2];
    const int tid = threadIdx.x;
    const int wave = tid >> 6, lane = tid & 63;

    const float mb1 = mx[(s * 4 + b) * HD + lane] + ba[lane];
    const float mb2 = mx[(s * 4 + b) * HD + lane + 64] + ba[lane + 64];
    const float wv1a = wv[lane], wv1b = wv[lane + 64];
    const float wv2a = wv[128 + lane], wv2b = wv[192 + lane];

    for (int jj = 0; jj < 64; ++jj) {
        int j = wave + jj * 8;
        float p1 = po[(size_t)j * HD + lane], p2 = po[(size_t)j * HD + lane + 64];
        float r1 = tanhf(mb1 + p1), r2 = tanhf(mb2 + p2);
        float sc = lb[(size_t)j * HD + lane] * wv1a + lb[(size_t)j * HD + lane + 64] * wv1b
                 + r1 * wv2a + r2 * wv2b;
        #pragma unroll
        for (int o = 32; o; o >>= 1) sc += __shfl_down(sc, o, 64);
        if (lane == 0) sl[j] = sc + bias;
    }
    __syncthreads();

    float v = sl[tid];
    float m = v;
    #pragma unroll
    for (int o = 32; o; o >>= 1) m = fmaxf(m, __shfl_xor(m, o, 64));
    if (lane == 0) red[wave] = m;
    __syncthreads();
    if (tid == 0) { float mm = red[0]; for (int i = 1; i < 8; ++i) mm = fmaxf(mm, red[i]); bcast[0] = mm; }
    __syncthreads();
    float e = __expf(v - bcast[0]);
    float ssum = e;
    #pragma unroll
    for (int o = 32; o; o >>= 1) ssum += __shfl_xor(ssum, o, 64);
    if (lane == 0) red[wave] = ssum;
    __syncthreads();
    if (tid == 0) { float tt = 0.f; for (int i = 0; i < 8; ++i) tt += red[i]; bcast[1] = tt; }
    __syncthreads();
    sl[tid] = e / bcast[1];
    __syncthreads();

    const int h = tid & 127, q4 = tid >> 7;
    const float mbh = mx[(s * 4 + b) * HD + h] + ba[h];
    float acc = 0.f;
    for (int jj = 0; jj < 128; ++jj) {
        int j = q4 + jj * 4;
        float r = tanhf(mbh + po[(size_t)j * HD + h]);
        acc += sl[j] * r;
    }
    red[tid] = acc;
    __syncthreads();
    if (tid < 128)
        feat[(s * 4 + b) * HD + tid] = red[tid] + red[128 + tid] + red[256 + tid] + red[384 + tid];
}

// ---------------- K5: final classifier + log_softmax + argmax (fp32 out) ----------------
__global__ void k5_final(const float* __restrict__ feat,
                         const float* __restrict__ wlast, const float* __restrict__ blast,
                         float* __restrict__ outp)
{
    const int tid = threadIdx.x;
    if (tid < 4) {
        const int b = tid;
        float l0 = blast[0], l1 = blast[1];
        for (int k = 0; k < 256; ++k) {
            float f = (k < 128) ? feat[b * HD + k] : feat[(4 + b) * HD + (k - 128)];
            l0 += f * wlast[k * 2 + 0];
            l1 += f * wlast[k * 2 + 1];
        }
        float mxl = fmaxf(l0, l1);
        float lse = mxl + logf(__expf(l0 - mxl) + __expf(l1 - mxl));
        outp[b * 2 + 0] = l0 - lse;
        outp[b * 2 + 1] = l1 - lse;
        outp[8 + b]     = (l1 > l0) ? 1.f : 0.f;
    }
}

extern "C" void kernel_launch(void* const* d_in, const int* in_sizes, int n_in,
                              void* d_out, int out_size, void* d_ws, size_t ws_size,
                              hipStream_t stream)
{
    const int*   qc    = (const int*)d_in[0];
    const int*   ac    = (const int*)d_in[1];
    const float* emb   = (const float*)d_in[2];
    const float* wih   = (const float*)d_in[3];
    const float* whh   = (const float*)d_in[4];
    const float* bl    = (const float*)d_in[5];
    const float* wa    = (const float*)d_in[6];
    const float* ba    = (const float*)d_in[7];
    const float* wq    = (const float*)d_in[8];
    const float* bq    = (const float*)d_in[9];
    const float* wans  = (const float*)d_in[10];
    const float* bans  = (const float*)d_in[11];
    const float* wlast = (const float*)d_in[12];
    const float* blast = (const float*)d_in[13];

    float* ws   = (float*)d_ws;
    float* preg = ws;
    float* lstm = ws + OFF_LSTM;
    float* proj = ws + OFF_PROJ;
    float* mx   = ws + OFF_MX;
    float* feat = ws + OFF_FEAT;

    k1_gemm<<<dim3(64, 8), 256, 0, stream>>>(qc, ac, emb, wih, bl, preg);
    k2_lstm_mfma<<<1, 512, 0, stream>>>(whh, preg, lstm);
    k3_proj<<<64, 512, 0, stream>>>(wa, lstm, proj);
    k3_max<<<8, 128, 0, stream>>>(proj, mx);
    k4_attn<<<8, 512, 0, stream>>>(lstm, proj, mx, ba, wq, bq, wans, bans, feat);
    k5_final<<<1, 64, 0, stream>>>(feat, wlast, blast, (float*)d_out);
}

// Round 4
// 747.227 us; speedup vs baseline: 1.0775x; 1.0775x over previous
//
#include <hip/hip_runtime.h>
#include <hip/hip_bf16.h>

#define EMBED 300
#define HD    128
#define LLEN  512
#define G4    512   // 4*H

// Workspace layout (floats):
#define OFF_LSTM 2097152
#define OFF_PROJ 2621440
#define OFF_MX   3145728
#define OFF_FEAT 3146752

typedef _Float16 half8 __attribute__((ext_vector_type(8)));
typedef float    f32x4 __attribute__((ext_vector_type(4)));

// ---------------- K1: embedding gather + X @ W_ih + b  → pre_g ----------------
__global__ __launch_bounds__(256) void k1_gemm(
    const int* __restrict__ qc, const int* __restrict__ ac,
    const float* __restrict__ emb, const float* __restrict__ wih,
    const float* __restrict__ bl, float* __restrict__ preg)
{
    __shared__ float As[32][65];
    __shared__ float Bs[32][64];
    const int m0 = blockIdx.x * 64;
    const int n0 = blockIdx.y * 64;
    const int tid = threadIdx.x;
    const int tx = tid & 15, ty = tid >> 4;
    float acc[4][4] = {};

    for (int k0 = 0; k0 < 300; k0 += 32) {
        #pragma unroll
        for (int i = 0; i < 8; ++i) {
            int e = tid + i * 256;
            int m = e >> 5, kk = e & 31;
            int row = m0 + m;
            int c = row >> 11, b = (row >> 9) & 3, t = row & 511;
            int tok = (c == 0 ? qc : ac)[b * LLEN + t];
            int k = k0 + kk;
            As[kk][m] = (k < 300) ? emb[(size_t)tok * EMBED + k] : 0.f;
        }
        #pragma unroll
        for (int i = 0; i < 8; ++i) {
            int e = tid + i * 256;
            int kk = e >> 6, n = e & 63;
            int k = k0 + kk;
            Bs[kk][n] = (k < 300) ? wih[k * G4 + n0 + n] : 0.f;
        }
        __syncthreads();
        #pragma unroll
        for (int kk = 0; kk < 32; ++kk) {
            float a[4], bv[4];
            #pragma unroll
            for (int i = 0; i < 4; ++i) a[i] = As[kk][ty * 4 + i];
            #pragma unroll
            for (int j = 0; j < 4; ++j) bv[j] = Bs[kk][tx * 4 + j];
            #pragma unroll
            for (int i = 0; i < 4; ++i)
                #pragma unroll
                for (int j = 0; j < 4; ++j)
                    acc[i][j] += a[i] * bv[j];
        }
        __syncthreads();
    }
    #pragma unroll
    for (int i = 0; i < 4; ++i) {
        int row = m0 + ty * 4 + i;
        #pragma unroll
        for (int j = 0; j < 4; ++j) {
            int n = n0 + tx * 4 + j;
            preg[(size_t)row * G4 + n] = acc[i][j] + bl[n];
        }
    }
}

// ---------------- K2: MFMA LSTM scan, raw barriers, h double-buffer ----------------
__device__ __forceinline__ float fsig(float x) {
    return __fdividef(1.f, 1.f + __expf(-x));
}
__device__ __forceinline__ float ftanh(float x) {
    return 1.f - __fdividef(2.f, __expf(2.f * x) + 1.f);
}

__global__ __launch_bounds__(512, 2) void k2_lstm_mfma(
    const float* __restrict__ whh, const float* __restrict__ preg,
    float* __restrict__ lstm)
{
    const int tid = threadIdx.x;
    const int w  = tid >> 6;      // wave 0..7
    const int l  = tid & 63;
    const int li = l & 15;        // D col (seq slot, mod 8)
    const int g  = l >> 4;        // k-block / D row-block
    const bool low = li < 8;

    __shared__ __align__(16) _Float16 h0[8 * 136];
    __shared__ __align__(16) _Float16 h1[8 * 136];

    // static A fragments: A[m][k] = Whh[k][mg], mg = s*128 + w*16 + li
    half8 afrag[4][4];
    #pragma unroll
    for (int s = 0; s < 4; ++s) {
        const int mg = s * 128 + w * 16 + li;
        #pragma unroll
        for (int kt = 0; kt < 4; ++kt) {
            half8 v;
            #pragma unroll
            for (int e = 0; e < 8; ++e)
                v[e] = (_Float16)whh[(kt * 32 + g * 8 + e) * G4 + mg];
            afrag[kt][s] = v;
        }
    }

    for (int i = tid; i < 8 * 136; i += 512) { h0[i] = (_Float16)0.f; h1[i] = (_Float16)0.f; }

    const int seq = li & 7;
    const f32x4* pg4 = (const f32x4*)(preg + (size_t)seq * LLEN * G4);
    const int pgo = w * 4 + g;                 // + t*128 + s*32
    const int uA = w * 16 + g * 4 + (low ? 0 : 2);
    float* outp = lstm + (size_t)seq * LLEN * HD + uA;
    float cA = 0.f, cB = 0.f;

    f32x4 pgA[4], pgB[4];
    #pragma unroll
    for (int s = 0; s < 4; ++s) pgA[s] = pg4[0 * 128 + s * 32 + pgo];
    #pragma unroll
    for (int s = 0; s < 4; ++s) pgB[s] = pg4[1 * 128 + s * 32 + pgo];

    __syncthreads();

#define LSTM_STEP(T, PGV, RD, WR)                                              \
    {                                                                          \
        const _Float16* hp = (RD) + seq * 136;                                 \
        half8 bfrag[4];                                                        \
        _Pragma("unroll")                                                      \
        for (int kt = 0; kt < 4; ++kt)                                         \
            bfrag[kt] = *(const half8*)(hp + kt * 32 + g * 8);                 \
        f32x4 acc[4];                                                          \
        _Pragma("unroll")                                                      \
        for (int s = 0; s < 4; ++s) acc[s] = PGV[s];                           \
        _Pragma("unroll")                                                      \
        for (int kt = 0; kt < 4; ++kt) {                                       \
            _Pragma("unroll")                                                  \
            for (int s = 0; s < 4; ++s)                                        \
                acc[s] = __builtin_amdgcn_mfma_f32_16x16x32_f16(               \
                    afrag[kt][s], bfrag[kt], acc[s], 0, 0, 0);                 \
        }                                                                      \
        {                                                                      \
            int tp = (T) + 2; if (tp > 511) tp = 511;                          \
            _Pragma("unroll")                                                  \
            for (int s = 0; s < 4; ++s) PGV[s] = pg4[tp * 128 + s * 32 + pgo]; \
        }                                                                      \
        float xi = low ? acc[0][0] : acc[0][2];                                \
        float xf = low ? acc[1][0] : acc[1][2];                                \
        float xg = low ? acc[2][0] : acc[2][2];                                \
        float xo = low ? acc[3][0] : acc[3][2];                                \
        float yi = low ? acc[0][1] : acc[0][3];                                \
        float yf = low ? acc[1][1] : acc[1][3];                                \
        float yg = low ? acc[2][1] : acc[2][3];                                \
        float yo = low ? acc[3][1] : acc[3][3];                                \
        float iA = fsig(xi), fA = fsig(xf), gA = ftanh(xg), oA = fsig(xo);     \
        cA = fA * cA + iA * gA;                                                \
        float hA = oA * ftanh(cA);                                             \
        float iB = fsig(yi), fB = fsig(yf), gB = ftanh(yg), oB = fsig(yo);     \
        cB = fB * cB + iB * gB;                                                \
        float hB = oB * ftanh(cB);                                             \
        *(float2*)(outp + (size_t)(T) * HD) = make_float2(hA, hB);             \
        union { _Float16 hh[2]; unsigned u; } pk;                              \
        pk.hh[0] = (_Float16)hA; pk.hh[1] = (_Float16)hB;                      \
        *(unsigned*)((WR) + seq * 136 + uA) = pk.u;                            \
        asm volatile("s_waitcnt lgkmcnt(0)" ::: "memory");                     \
        __builtin_amdgcn_sched_barrier(0);                                     \
        __builtin_amdgcn_s_barrier();                                          \
        __builtin_amdgcn_sched_barrier(0);                                     \
    }

    #pragma unroll 1
    for (int tt = 0; tt < 256; ++tt) {
        const int t0 = tt * 2;
        LSTM_STEP(t0,     pgA, h0, h1);
        LSTM_STEP(t0 + 1, pgB, h1, h0);
    }
#undef LSTM_STEP
}

// ---------------- K3: proj = lstm @ Wa_part (per side). 64 WGs ----------------
__global__ __launch_bounds__(512) void k3_proj(
    const float* __restrict__ wa, const float* __restrict__ lstm,
    float* __restrict__ proj)
{
    const int idx = blockIdx.x;
    const int tc = idx & 7, b = (idx >> 3) & 3, s = idx >> 5;
    __shared__ float wsm[128][128];
    const int tid = threadIdx.x;
    #pragma unroll
    for (int i = 0; i < 32; ++i) {
        int e = tid + i * 512;
        int k = e >> 7, h = e & 127;
        wsm[k][h] = wa[(s * 128 + k) * 128 + h];
    }
    __syncthreads();
    const float* lb = lstm + ((size_t)(s * 4 + b)) * LLEN * HD;
    float* pb = proj + ((size_t)(s * 4 + b)) * LLEN * HD;
    const int h = tid & 127, ts = tid >> 7;
    for (int i = 0; i < 16; ++i) {
        int t = tc * 64 + i * 4 + ts;
        const float* lr = lb + (size_t)t * HD;
        float acc = 0.f;
        #pragma unroll
        for (int k = 0; k < 128; ++k) acc += lr[k] * wsm[k][h];
        pb[(size_t)t * HD + h] = acc;
    }
}

// ---------------- K3b: per-(side,b,h) max over t ----------------
__global__ void k3_max(const float* __restrict__ proj, float* __restrict__ mx)
{
    const int cb = blockIdx.x;
    const int h = threadIdx.x;
    const float* p = proj + (size_t)cb * LLEN * HD;
    float m = -1e30f;
    #pragma unroll 8
    for (int t = 0; t < LLEN; ++t) m = fmaxf(m, p[(size_t)t * HD + h]);
    mx[cb * HD + h] = m;
}

// ---------------- K4: r (on the fly) + scores + softmax + feature ----------------
__global__ __launch_bounds__(512) void k4_attn(
    const float* __restrict__ lstm, const float* __restrict__ proj,
    const float* __restrict__ mx, const float* __restrict__ ba,
    const float* __restrict__ wq, const float* __restrict__ bq,
    const float* __restrict__ wans, const float* __restrict__ bans,
    float* __restrict__ feat)
{
    const int blk = blockIdx.x;
    const int s = blk >> 2, b = blk & 3;
    const float* wv = (s == 0) ? wq : wans;
    const float bias = (s == 0) ? bq[0] : bans[0];
    const float* lb = lstm + ((size_t)(s * 4 + b)) * LLEN * HD;
    const float* po = proj + ((size_t)((1 - s) * 4 + b)) * LLEN * HD;
    __shared__ float sl[512];
    __shared__ float red[512];
    __shared__ float bcast[2];
    const int tid = threadIdx.x;
    const int wave = tid >> 6, lane = tid & 63;

    const float mb1 = mx[(s * 4 + b) * HD + lane] + ba[lane];
    const float mb2 = mx[(s * 4 + b) * HD + lane + 64] + ba[lane + 64];
    const float wv1a = wv[lane], wv1b = wv[lane + 64];
    const float wv2a = wv[128 + lane], wv2b = wv[192 + lane];

    for (int jj = 0; jj < 64; ++jj) {
        int j = wave + jj * 8;
        float p1 = po[(size_t)j * HD + lane], p2 = po[(size_t)j * HD + lane + 64];
        float r1 = tanhf(mb1 + p1), r2 = tanhf(mb2 + p2);
        float sc = lb[(size_t)j * HD + lane] * wv1a + lb[(size_t)j * HD + lane + 64] * wv1b
                 + r1 * wv2a + r2 * wv2b;
        #pragma unroll
        for (int o = 32; o; o >>= 1) sc += __shfl_down(sc, o, 64);
        if (lane == 0) sl[j] = sc + bias;
    }
    __syncthreads();

    float v = sl[tid];
    float m = v;
    #pragma unroll
    for (int o = 32; o; o >>= 1) m = fmaxf(m, __shfl_xor(m, o, 64));
    if (lane == 0) red[wave] = m;
    __syncthreads();
    if (tid == 0) { float mm = red[0]; for (int i = 1; i < 8; ++i) mm = fmaxf(mm, red[i]); bcast[0] = mm; }
    __syncthreads();
    float e = __expf(v - bcast[0]);
    float ssum = e;
    #pragma unroll
    for (int o = 32; o; o >>= 1) ssum += __shfl_xor(ssum, o, 64);
    if (lane == 0) red[wave] = ssum;
    __syncthreads();
    if (tid == 0) { float tt = 0.f; for (int i = 0; i < 8; ++i) tt += red[i]; bcast[1] = tt; }
    __syncthreads();
    sl[tid] = e / bcast[1];
    __syncthreads();

    const int h = tid & 127, q4 = tid >> 7;
    const float mbh = mx[(s * 4 + b) * HD + h] + ba[h];
    float acc = 0.f;
    for (int jj = 0; jj < 128; ++jj) {
        int j = q4 + jj * 4;
        float r = tanhf(mbh + po[(size_t)j * HD + h]);
        acc += sl[j] * r;
    }
    red[tid] = acc;
    __syncthreads();
    if (tid < 128)
        feat[(s * 4 + b) * HD + tid] = red[tid] + red[128 + tid] + red[256 + tid] + red[384 + tid];
}

// ---------------- K5: final classifier + log_softmax + argmax (fp32 out) ----------------
__global__ void k5_final(const float* __restrict__ feat,
                         const float* __restrict__ wlast, const float* __restrict__ blast,
                         float* __restrict__ outp)
{
    const int tid = threadIdx.x;
    if (tid < 4) {
        const int b = tid;
        float l0 = blast[0], l1 = blast[1];
        for (int k = 0; k < 256; ++k) {
            float f = (k < 128) ? feat[b * HD + k] : feat[(4 + b) * HD + (k - 128)];
            l0 += f * wlast[k * 2 + 0];
            l1 += f * wlast[k * 2 + 1];
        }
        float mxl = fmaxf(l0, l1);
        float lse = mxl + logf(__expf(l0 - mxl) + __expf(l1 - mxl));
        outp[b * 2 + 0] = l0 - lse;
        outp[b * 2 + 1] = l1 - lse;
        outp[8 + b]     = (l1 > l0) ? 1.f : 0.f;
    }
}

extern "C" void kernel_launch(void* const* d_in, const int* in_sizes, int n_in,
                              void* d_out, int out_size, void* d_ws, size_t ws_size,
                              hipStream_t stream)
{
    const int*   qc    = (const int*)d_in[0];
    const int*   ac    = (const int*)d_in[1];
    const float* emb   = (const float*)d_in[2];
    const float* wih   = (const float*)d_in[3];
    const float* whh   = (const float*)d_in[4];
    const float* bl    = (const float*)d_in[5];
    const float* wa    = (const float*)d_in[6];
    const float* ba    = (const float*)d_in[7];
    const float* wq    = (const float*)d_in[8];
    const float* bq    = (const float*)d_in[9];
    const float* wans  = (const float*)d_in[10];
    const float* bans  = (const float*)d_in[11];
    const float* wlast = (const float*)d_in[12];
    const float* blast = (const float*)d_in[13];

    float* ws   = (float*)d_ws;
    float* preg = ws;
    float* lstm = ws + OFF_LSTM;
    float* proj = ws + OFF_PROJ;
    float* mx   = ws + OFF_MX;
    float* feat = ws + OFF_FEAT;

    k1_gemm<<<dim3(64, 8), 256, 0, stream>>>(qc, ac, emb, wih, bl, preg);
    k2_lstm_mfma<<<1, 512, 0, stream>>>(whh, preg, lstm);
    k3_proj<<<64, 512, 0, stream>>>(wa, lstm, proj);
    k3_max<<<8, 128, 0, stream>>>(proj, mx);
    k4_attn<<<8, 512, 0, stream>>>(lstm, proj, mx, ba, wq, bq, wans, bans, feat);
    k5_final<<<1, 64, 0, stream>>>(feat, wlast, blast, (float*)d_out);
}

// Round 5
// 593.436 us; speedup vs baseline: 1.3568x; 1.2592x over previous
//
#include <hip/hip_runtime.h>
#include <hip/hip_bf16.h>

#define EMBED 300
#define HD    128
#define LLEN  512
#define G4    512   // 4*H

// Workspace layout (floats):
#define OFF_LSTM 2097152
#define OFF_PROJ 2621440
#define OFF_MX   3145728
#define OFF_FEAT 3146752

typedef _Float16 half8 __attribute__((ext_vector_type(8)));
typedef float    f32x4 __attribute__((ext_vector_type(4)));

// ---------------- K1: embedding gather + X @ W_ih + b  → pre_g ----------------
__global__ __launch_bounds__(256) void k1_gemm(
    const int* __restrict__ qc, const int* __restrict__ ac,
    const float* __restrict__ emb, const float* __restrict__ wih,
    const float* __restrict__ bl, float* __restrict__ preg)
{
    __shared__ float As[32][65];
    __shared__ float Bs[32][64];
    const int m0 = blockIdx.x * 64;
    const int n0 = blockIdx.y * 64;
    const int tid = threadIdx.x;
    const int tx = tid & 15, ty = tid >> 4;
    float acc[4][4] = {};

    for (int k0 = 0; k0 < 300; k0 += 32) {
        #pragma unroll
        for (int i = 0; i < 8; ++i) {
            int e = tid + i * 256;
            int m = e >> 5, kk = e & 31;
            int row = m0 + m;
            int c = row >> 11, b = (row >> 9) & 3, t = row & 511;
            int tok = (c == 0 ? qc : ac)[b * LLEN + t];
            int k = k0 + kk;
            As[kk][m] = (k < 300) ? emb[(size_t)tok * EMBED + k] : 0.f;
        }
        #pragma unroll
        for (int i = 0; i < 8; ++i) {
            int e = tid + i * 256;
            int kk = e >> 6, n = e & 63;
            int k = k0 + kk;
            Bs[kk][n] = (k < 300) ? wih[k * G4 + n0 + n] : 0.f;
        }
        __syncthreads();
        #pragma unroll
        for (int kk = 0; kk < 32; ++kk) {
            float a[4], bv[4];
            #pragma unroll
            for (int i = 0; i < 4; ++i) a[i] = As[kk][ty * 4 + i];
            #pragma unroll
            for (int j = 0; j < 4; ++j) bv[j] = Bs[kk][tx * 4 + j];
            #pragma unroll
            for (int i = 0; i < 4; ++i)
                #pragma unroll
                for (int j = 0; j < 4; ++j)
                    acc[i][j] += a[i] * bv[j];
        }
        __syncthreads();
    }
    #pragma unroll
    for (int i = 0; i < 4; ++i) {
        int row = m0 + ty * 4 + i;
        #pragma unroll
        for (int j = 0; j < 4; ++j) {
            int n = n0 + tx * 4 + j;
            preg[(size_t)row * G4 + n] = acc[i][j] + bl[n];
        }
    }
}

// ---------------- K2: MFMA LSTM scan, 8 WGs (1 seq/CU), broadcast-B ----------------
// Per WG: D[m][n] = Whh^T(512x128) @ h(128) replicated over all 16 columns.
// Every thread (g,li) holds 4 complete cells locally (acc[s][0..3], cols dup);
// lanes li<4 own cell unit = w*16 + g*4 + li. TRANS work spread over 8 CUs.
__device__ __forceinline__ float fsig(float x) {
    return __fdividef(1.f, 1.f + __expf(-x));
}
__device__ __forceinline__ float ftanh(float x) {
    return 1.f - __fdividef(2.f, __expf(2.f * x) + 1.f);
}

__global__ __launch_bounds__(512, 2) void k2_lstm_mfma(
    const float* __restrict__ whh, const float* __restrict__ preg,
    float* __restrict__ lstm)
{
    const int seq = blockIdx.x;          // 0..7
    const int tid = threadIdx.x;
    const int w  = tid >> 6;             // wave 0..7 -> units w*16..w*16+15
    const int l  = tid & 63;
    const int li = l & 15;
    const int g  = l >> 4;

    __shared__ __align__(16) _Float16 h0[128];
    __shared__ __align__(16) _Float16 h1[128];

    // static A fragments: A[m=li][k=kt*32+g*8+e] = Whh[k][mg], mg = s*128 + w*16 + li
    half8 afrag[4][4];
    #pragma unroll
    for (int s = 0; s < 4; ++s) {
        const int mg = s * 128 + w * 16 + li;
        #pragma unroll
        for (int kt = 0; kt < 4; ++kt) {
            half8 v;
            #pragma unroll
            for (int e = 0; e < 8; ++e)
                v[e] = (_Float16)whh[(kt * 32 + g * 8 + e) * G4 + mg];
            afrag[kt][s] = v;
        }
    }

    if (tid < 128) { h0[tid] = (_Float16)0.f; h1[tid] = (_Float16)0.f; }

    const f32x4* pg4 = (const f32x4*)(preg + (size_t)seq * LLEN * G4);
    const int pgo = w * 4 + g;           // f32x4 idx; + t*128 + s*32 (li-independent!)
    const bool cellane = li < 4;
    const int unit = w * 16 + g * 4 + li;        // valid for cellane
    float* outp = lstm + (size_t)seq * LLEN * HD + unit;
    float cst = 0.f;

    f32x4 pgA[4], pgB[4];
    #pragma unroll
    for (int s = 0; s < 4; ++s) pgA[s] = pg4[0 * 128 + s * 32 + pgo];
    #pragma unroll
    for (int s = 0; s < 4; ++s) pgB[s] = pg4[1 * 128 + s * 32 + pgo];

    __syncthreads();

#define LSTM_STEP(T, PGV, RD, WR)                                              \
    {                                                                          \
        half8 bfrag[4];                                                        \
        _Pragma("unroll")                                                      \
        for (int kt = 0; kt < 4; ++kt)                                         \
            bfrag[kt] = *(const half8*)((RD) + kt * 32 + g * 8);               \
        f32x4 a0 = PGV[0], a1 = PGV[1], a2 = PGV[2], a3 = PGV[3];              \
        _Pragma("unroll")                                                      \
        for (int kt = 0; kt < 4; ++kt) {                                       \
            a0 = __builtin_amdgcn_mfma_f32_16x16x32_f16(afrag[kt][0], bfrag[kt], a0, 0, 0, 0); \
            a1 = __builtin_amdgcn_mfma_f32_16x16x32_f16(afrag[kt][1], bfrag[kt], a1, 0, 0, 0); \
            a2 = __builtin_amdgcn_mfma_f32_16x16x32_f16(afrag[kt][2], bfrag[kt], a2, 0, 0, 0); \
            a3 = __builtin_amdgcn_mfma_f32_16x16x32_f16(afrag[kt][3], bfrag[kt], a3, 0, 0, 0); \
        }                                                                      \
        {                                                                      \
            int tp = (T) + 2; if (tp > 511) tp = 511;                          \
            _Pragma("unroll")                                                  \
            for (int s = 0; s < 4; ++s) PGV[s] = pg4[tp * 128 + s * 32 + pgo]; \
        }                                                                      \
        if (cellane) {                                                         \
            float xi = (li == 0) ? a0[0] : (li == 1) ? a0[1] : (li == 2) ? a0[2] : a0[3]; \
            float xf = (li == 0) ? a1[0] : (li == 1) ? a1[1] : (li == 2) ? a1[2] : a1[3]; \
            float xg = (li == 0) ? a2[0] : (li == 1) ? a2[1] : (li == 2) ? a2[2] : a2[3]; \
            float xo = (li == 0) ? a3[0] : (li == 1) ? a3[1] : (li == 2) ? a3[2] : a3[3]; \
            float i_ = fsig(xi), f_ = fsig(xf), g_ = ftanh(xg), o_ = fsig(xo); \
            cst = f_ * cst + i_ * g_;                                          \
            float h = o_ * ftanh(cst);                                         \
            outp[(size_t)(T) * HD] = h;                                        \
            (WR)[unit] = (_Float16)h;                                          \
        }                                                                      \
        asm volatile("s_waitcnt lgkmcnt(0)" ::: "memory");                     \
        __builtin_amdgcn_sched_barrier(0);                                     \
        __builtin_amdgcn_s_barrier();                                          \
        __builtin_amdgcn_sched_barrier(0);                                     \
    }

    #pragma unroll 1
    for (int tt = 0; tt < 256; ++tt) {
        const int t0 = tt * 2;
        LSTM_STEP(t0,     pgA, h0, h1);
        LSTM_STEP(t0 + 1, pgB, h1, h0);
    }
#undef LSTM_STEP
}

// ---------------- K3: proj = lstm @ Wa_part (per side). 64 WGs ----------------
__global__ __launch_bounds__(512) void k3_proj(
    const float* __restrict__ wa, const float* __restrict__ lstm,
    float* __restrict__ proj)
{
    const int idx = blockIdx.x;
    const int tc = idx & 7, b = (idx >> 3) & 3, s = idx >> 5;
    __shared__ float wsm[128][128];
    const int tid = threadIdx.x;
    #pragma unroll
    for (int i = 0; i < 32; ++i) {
        int e = tid + i * 512;
        int k = e >> 7, h = e & 127;
        wsm[k][h] = wa[(s * 128 + k) * 128 + h];
    }
    __syncthreads();
    const float* lb = lstm + ((size_t)(s * 4 + b)) * LLEN * HD;
    float* pb = proj + ((size_t)(s * 4 + b)) * LLEN * HD;
    const int h = tid & 127, ts = tid >> 7;
    for (int i = 0; i < 16; ++i) {
        int t = tc * 64 + i * 4 + ts;
        const float* lr = lb + (size_t)t * HD;
        float acc = 0.f;
        #pragma unroll
        for (int k = 0; k < 128; ++k) acc += lr[k] * wsm[k][h];
        pb[(size_t)t * HD + h] = acc;
    }
}

// ---------------- K3b: per-(side,b,h) max over t ----------------
__global__ void k3_max(const float* __restrict__ proj, float* __restrict__ mx)
{
    const int cb = blockIdx.x;
    const int h = threadIdx.x;
    const float* p = proj + (size_t)cb * LLEN * HD;
    float m = -1e30f;
    #pragma unroll 8
    for (int t = 0; t < LLEN; ++t) m = fmaxf(m, p[(size_t)t * HD + h]);
    mx[cb * HD + h] = m;
}

// ---------------- K4: r (on the fly) + scores + softmax + feature ----------------
__global__ __launch_bounds__(512) void k4_attn(
    const float* __restrict__ lstm, const float* __restrict__ proj,
    const float* __restrict__ mx, const float* __restrict__ ba,
    const float* __restrict__ wq, const float* __restrict__ bq,
    const float* __restrict__ wans, const float* __restrict__ bans,
    float* __restrict__ feat)
{
    const int blk = blockIdx.x;
    const int s = blk >> 2, b = blk & 3;
    const float* wv = (s == 0) ? wq : wans;
    const float bias = (s == 0) ? bq[0] : bans[0];
    const float* lb = lstm + ((size_t)(s * 4 + b)) * LLEN * HD;
    const float* po = proj + ((size_t)((1 - s) * 4 + b)) * LLEN * HD;
    __shared__ float sl[512];
    __shared__ float red[512];
    __shared__ float bcast[2];
    const int tid = threadIdx.x;
    const int wave = tid >> 6, lane = tid & 63;

    const float mb1 = mx[(s * 4 + b) * HD + lane] + ba[lane];
    const float mb2 = mx[(s * 4 + b) * HD + lane + 64] + ba[lane + 64];
    const float wv1a = wv[lane], wv1b = wv[lane + 64];
    const float wv2a = wv[128 + lane], wv2b = wv[192 + lane];

    for (int jj = 0; jj < 64; ++jj) {
        int j = wave + jj * 8;
        float p1 = po[(size_t)j * HD + lane], p2 = po[(size_t)j * HD + lane + 64];
        float r1 = tanhf(mb1 + p1), r2 = tanhf(mb2 + p2);
        float sc = lb[(size_t)j * HD + lane] * wv1a + lb[(size_t)j * HD + lane + 64] * wv1b
                 + r1 * wv2a + r2 * wv2b;
        #pragma unroll
        for (int o = 32; o; o >>= 1) sc += __shfl_down(sc, o, 64);
        if (lane == 0) sl[j] = sc + bias;
    }
    __syncthreads();

    float v = sl[tid];
    float m = v;
    #pragma unroll
    for (int o = 32; o; o >>= 1) m = fmaxf(m, __shfl_xor(m, o, 64));
    if (lane == 0) red[wave] = m;
    __syncthreads();
    if (tid == 0) { float mm = red[0]; for (int i = 1; i < 8; ++i) mm = fmaxf(mm, red[i]); bcast[0] = mm; }
    __syncthreads();
    float e = __expf(v - bcast[0]);
    float ssum = e;
    #pragma unroll
    for (int o = 32; o; o >>= 1) ssum += __shfl_xor(ssum, o, 64);
    if (lane == 0) red[wave] = ssum;
    __syncthreads();
    if (tid == 0) { float tt = 0.f; for (int i = 0; i < 8; ++i) tt += red[i]; bcast[1] = tt; }
    __syncthreads();
    sl[tid] = e / bcast[1];
    __syncthreads();

    const int h = tid & 127, q4 = tid >> 7;
    const float mbh = mx[(s * 4 + b) * HD + h] + ba[h];
    float acc = 0.f;
    for (int jj = 0; jj < 128; ++jj) {
        int j = q4 + jj * 4;
        float r = tanhf(mbh + po[(size_t)j * HD + h]);
        acc += sl[j] * r;
    }
    red[tid] = acc;
    __syncthreads();
    if (tid < 128)
        feat[(s * 4 + b) * HD + tid] = red[tid] + red[128 + tid] + red[256 + tid] + red[384 + tid];
}

// ---------------- K5: final classifier + log_softmax + argmax (fp32 out) ----------------
__global__ void k5_final(const float* __restrict__ feat,
                         const float* __restrict__ wlast, const float* __restrict__ blast,
                         float* __restrict__ outp)
{
    const int tid = threadIdx.x;
    if (tid < 4) {
        const int b = tid;
        float l0 = blast[0], l1 = blast[1];
        for (int k = 0; k < 256; ++k) {
            float f = (k < 128) ? feat[b * HD + k] : feat[(4 + b) * HD + (k - 128)];
            l0 += f * wlast[k * 2 + 0];
            l1 += f * wlast[k * 2 + 1];
        }
        float mxl = fmaxf(l0, l1);
        float lse = mxl + logf(__expf(l0 - mxl) + __expf(l1 - mxl));
        outp[b * 2 + 0] = l0 - lse;
        outp[b * 2 + 1] = l1 - lse;
        outp[8 + b]     = (l1 > l0) ? 1.f : 0.f;
    }
}

extern "C" void kernel_launch(void* const* d_in, const int* in_sizes, int n_in,
                              void* d_out, int out_size, void* d_ws, size_t ws_size,
                              hipStream_t stream)
{
    const int*   qc    = (const int*)d_in[0];
    const int*   ac    = (const int*)d_in[1];
    const float* emb   = (const float*)d_in[2];
    const float* wih   = (const float*)d_in[3];
    const float* whh   = (const float*)d_in[4];
    const float* bl    = (const float*)d_in[5];
    const float* wa    = (const float*)d_in[6];
    const float* ba    = (const float*)d_in[7];
    const float* wq    = (const float*)d_in[8];
    const float* bq    = (const float*)d_in[9];
    const float* wans  = (const float*)d_in[10];
    const float* bans  = (const float*)d_in[11];
    const float* wlast = (const float*)d_in[12];
    const float* blast = (const float*)d_in[13];

    float* ws   = (float*)d_ws;
    float* preg = ws;
    float* lstm = ws + OFF_LSTM;
    float* proj = ws + OFF_PROJ;
    float* mx   = ws + OFF_MX;
    float* feat = ws + OFF_FEAT;

    k1_gemm<<<dim3(64, 8), 256, 0, stream>>>(qc, ac, emb, wih, bl, preg);
    k2_lstm_mfma<<<8, 512, 0, stream>>>(whh, preg, lstm);
    k3_proj<<<64, 512, 0, stream>>>(wa, lstm, proj);
    k3_max<<<8, 128, 0, stream>>>(proj, mx);
    k4_attn<<<8, 512, 0, stream>>>(lstm, proj, mx, ba, wq, bq, wans, bans, feat);
    k5_final<<<1, 64, 0, stream>>>(feat, wlast, blast, (float*)d_out);
}

// Round 6
// 551.037 us; speedup vs baseline: 1.4612x; 1.0769x over previous
//
#include <hip/hip_runtime.h>
#include <hip/hip_bf16.h>

#define EMBED 300
#define HD    128
#define LLEN  512
#define G4    512   // 4*H

// Workspace layout (floats):
#define OFF_LSTM 2097152
#define OFF_PROJ 2621440
#define OFF_MX   3145728
#define OFF_FEAT 3146752

typedef _Float16 half8 __attribute__((ext_vector_type(8)));
typedef float    f32x4 __attribute__((ext_vector_type(4)));

__device__ __forceinline__ float fsig(float x) {
    return __fdividef(1.f, 1.f + __expf(-x));
}
__device__ __forceinline__ float ftanh(float x) {
    return 1.f - __fdividef(2.f, __expf(2.f * x) + 1.f);
}

// ---------------- K1: embedding gather + X @ W_ih + b  → pre_g ----------------
__global__ __launch_bounds__(256) void k1_gemm(
    const int* __restrict__ qc, const int* __restrict__ ac,
    const float* __restrict__ emb, const float* __restrict__ wih,
    const float* __restrict__ bl, float* __restrict__ preg)
{
    __shared__ float As[32][65];
    __shared__ float Bs[32][64];
    const int m0 = blockIdx.x * 64;
    const int n0 = blockIdx.y * 64;
    const int tid = threadIdx.x;
    const int tx = tid & 15, ty = tid >> 4;
    float acc[4][4] = {};

    for (int k0 = 0; k0 < 300; k0 += 32) {
        #pragma unroll
        for (int i = 0; i < 8; ++i) {
            int e = tid + i * 256;
            int m = e >> 5, kk = e & 31;
            int row = m0 + m;
            int c = row >> 11, b = (row >> 9) & 3, t = row & 511;
            int tok = (c == 0 ? qc : ac)[b * LLEN + t];
            int k = k0 + kk;
            As[kk][m] = (k < 300) ? emb[(size_t)tok * EMBED + k] : 0.f;
        }
        #pragma unroll
        for (int i = 0; i < 8; ++i) {
            int e = tid + i * 256;
            int kk = e >> 6, n = e & 63;
            int k = k0 + kk;
            Bs[kk][n] = (k < 300) ? wih[k * G4 + n0 + n] : 0.f;
        }
        __syncthreads();
        #pragma unroll
        for (int kk = 0; kk < 32; ++kk) {
            float a[4], bv[4];
            #pragma unroll
            for (int i = 0; i < 4; ++i) a[i] = As[kk][ty * 4 + i];
            #pragma unroll
            for (int j = 0; j < 4; ++j) bv[j] = Bs[kk][tx * 4 + j];
            #pragma unroll
            for (int i = 0; i < 4; ++i)
                #pragma unroll
                for (int j = 0; j < 4; ++j)
                    acc[i][j] += a[i] * bv[j];
        }
        __syncthreads();
    }
    #pragma unroll
    for (int i = 0; i < 4; ++i) {
        int row = m0 + ty * 4 + i;
        #pragma unroll
        for (int j = 0; j < 4; ++j) {
            int n = n0 + tx * 4 + j;
            preg[(size_t)row * G4 + n] = acc[i][j] + bl[n];
        }
    }
}

// ---------------- K2: MFMA LSTM scan, 8 WGs (1 seq/CU), broadcast-B ----------------
__global__ __launch_bounds__(512, 2) void k2_lstm_mfma(
    const float* __restrict__ whh, const float* __restrict__ preg,
    float* __restrict__ lstm)
{
    const int seq = blockIdx.x;          // 0..7
    const int tid = threadIdx.x;
    const int w  = tid >> 6;             // wave 0..7 -> units w*16..w*16+15
    const int l  = tid & 63;
    const int li = l & 15;
    const int g  = l >> 4;

    __shared__ __align__(16) _Float16 h0[128];
    __shared__ __align__(16) _Float16 h1[128];

    // static A fragments: A[m=li][k=kt*32+g*8+e] = Whh[k][mg], mg = s*128 + w*16 + li
    half8 afrag[4][4];
    #pragma unroll
    for (int s = 0; s < 4; ++s) {
        const int mg = s * 128 + w * 16 + li;
        #pragma unroll
        for (int kt = 0; kt < 4; ++kt) {
            half8 v;
            #pragma unroll
            for (int e = 0; e < 8; ++e)
                v[e] = (_Float16)whh[(kt * 32 + g * 8 + e) * G4 + mg];
            afrag[kt][s] = v;
        }
    }

    if (tid < 128) { h0[tid] = (_Float16)0.f; h1[tid] = (_Float16)0.f; }

    const f32x4* pg4 = (const f32x4*)(preg + (size_t)seq * LLEN * G4);
    const int pgo = w * 4 + g;           // f32x4 idx; + t*128 + s*32 (li-independent)
    const int r   = li & 3;
    const int unit = w * 16 + g * 4 + r;
    const bool wlane = li < 4;
    float* outp = lstm + (size_t)seq * LLEN * HD + unit;
    float cst = 0.f;

    f32x4 pgA[4], pgB[4];
    #pragma unroll
    for (int s = 0; s < 4; ++s) pgA[s] = pg4[0 * 128 + s * 32 + pgo];
    #pragma unroll
    for (int s = 0; s < 4; ++s) pgB[s] = pg4[1 * 128 + s * 32 + pgo];

    __syncthreads();

#define LSTM_STEP(T, PGV, RD, WR)                                              \
    {                                                                          \
        half8 bfrag[4];                                                        \
        _Pragma("unroll")                                                      \
        for (int kt = 0; kt < 4; ++kt)                                         \
            bfrag[kt] = *(const half8*)((RD) + kt * 32 + g * 8);               \
        f32x4 a0 = PGV[0], a1 = PGV[1], a2 = PGV[2], a3 = PGV[3];              \
        {                                                                      \
            int tp = (T) + 2; if (tp > 511) tp = 511;                          \
            _Pragma("unroll")                                                  \
            for (int s = 0; s < 4; ++s) PGV[s] = pg4[tp * 128 + s * 32 + pgo]; \
        }                                                                      \
        _Pragma("unroll")                                                      \
        for (int kt = 0; kt < 4; ++kt) {                                       \
            a0 = __builtin_amdgcn_mfma_f32_16x16x32_f16(afrag[kt][0], bfrag[kt], a0, 0, 0, 0); \
            a1 = __builtin_amdgcn_mfma_f32_16x16x32_f16(afrag[kt][1], bfrag[kt], a1, 0, 0, 0); \
            a2 = __builtin_amdgcn_mfma_f32_16x16x32_f16(afrag[kt][2], bfrag[kt], a2, 0, 0, 0); \
            a3 = __builtin_amdgcn_mfma_f32_16x16x32_f16(afrag[kt][3], bfrag[kt], a3, 0, 0, 0); \
        }                                                                      \
        float xi = (r == 0) ? a0[0] : (r == 1) ? a0[1] : (r == 2) ? a0[2] : a0[3]; \
        float xf = (r == 0) ? a1[0] : (r == 1) ? a1[1] : (r == 2) ? a1[2] : a1[3]; \
        float xg = (r == 0) ? a2[0] : (r == 1) ? a2[1] : (r == 2) ? a2[2] : a2[3]; \
        float xo = (r == 0) ? a3[0] : (r == 1) ? a3[1] : (r == 2) ? a3[2] : a3[3]; \
        float i_ = fsig(xi), f_ = fsig(xf), g_ = ftanh(xg), o_ = fsig(xo);     \
        cst = f_ * cst + i_ * g_;                                              \
        float h = o_ * ftanh(cst);                                             \
        if (wlane) {                                                           \
            outp[(size_t)(T) * HD] = h;                                        \
            (WR)[unit] = (_Float16)h;                                          \
        }                                                                      \
        asm volatile("s_waitcnt lgkmcnt(0)" ::: "memory");                     \
        __builtin_amdgcn_sched_barrier(0);                                     \
        __builtin_amdgcn_s_barrier();                                          \
        __builtin_amdgcn_sched_barrier(0);                                     \
    }

    #pragma unroll 1
    for (int tt = 0; tt < 256; ++tt) {
        const int t0 = tt * 2;
        LSTM_STEP(t0,     pgA, h0, h1);
        LSTM_STEP(t0 + 1, pgB, h1, h0);
    }
#undef LSTM_STEP
}

// ---------------- K3: proj = lstm @ Wa_part. Wa column in VGPRs, float4 row loads ----------------
// 32 WGs: (cb 0..7) x (chunk 0..3 of 128 t). 512 threads: h = tid&127, tg = tid>>7.
__global__ __launch_bounds__(512, 1) void k3_proj(
    const float* __restrict__ wa, const float* __restrict__ lstm,
    float* __restrict__ proj)
{
    const int idx = blockIdx.x;
    const int cb = idx >> 2, chunk = idx & 3;
    const int s = cb >> 2;
    const int tid = threadIdx.x;
    const int h = tid & 127, tg = tid >> 7;

    float wcol[128];
    #pragma unroll
    for (int k = 0; k < 128; ++k) wcol[k] = wa[(s * 128 + k) * 128 + h];

    const float* lb = lstm + (size_t)cb * LLEN * HD;
    float* pb = proj + (size_t)cb * LLEN * HD;

    #pragma unroll 1
    for (int i = 0; i < 32; ++i) {
        const int t = chunk * 128 + i * 4 + tg;
        const float4* row4 = (const float4*)(lb + (size_t)t * HD);
        float acc = 0.f;
        #pragma unroll
        for (int q = 0; q < 32; ++q) {
            float4 lv = row4[q];
            acc += lv.x * wcol[4 * q + 0];
            acc += lv.y * wcol[4 * q + 1];
            acc += lv.z * wcol[4 * q + 2];
            acc += lv.w * wcol[4 * q + 3];
        }
        pb[(size_t)t * HD + h] = acc;
    }
}

// ---------------- K3b: per-(side,b,h) max over t. float4 + LDS reduce ----------------
__global__ __launch_bounds__(512) void k3_max(
    const float* __restrict__ proj, float* __restrict__ mx)
{
    const int cb = blockIdx.x;           // 0..7
    const int tid = threadIdx.x;
    const int hq = tid & 31, tg = tid >> 5;   // 16 t-groups
    const float4* p4 = (const float4*)(proj + (size_t)cb * LLEN * HD);
    float4 m4 = make_float4(-1e30f, -1e30f, -1e30f, -1e30f);
    #pragma unroll 4
    for (int k = 0; k < 32; ++k) {
        const int t = tg + k * 16;
        float4 v = p4[t * 32 + hq];
        m4.x = fmaxf(m4.x, v.x); m4.y = fmaxf(m4.y, v.y);
        m4.z = fmaxf(m4.z, v.z); m4.w = fmaxf(m4.w, v.w);
    }
    __shared__ float4 red[16][32];
    red[tg][hq] = m4;
    __syncthreads();
    if (tg == 0) {
        float4 m = red[0][hq];
        #pragma unroll
        for (int i = 1; i < 16; ++i) {
            float4 v = red[i][hq];
            m.x = fmaxf(m.x, v.x); m.y = fmaxf(m.y, v.y);
            m.z = fmaxf(m.z, v.z); m.w = fmaxf(m.w, v.w);
        }
        ((float4*)mx)[cb * 32 + hq] = m;
    }
}

// ---------------- K4: r (on the fly) + scores + softmax + feature ----------------
__global__ __launch_bounds__(512) void k4_attn(
    const float* __restrict__ lstm, const float* __restrict__ proj,
    const float* __restrict__ mx, const float* __restrict__ ba,
    const float* __restrict__ wq, const float* __restrict__ bq,
    const float* __restrict__ wans, const float* __restrict__ bans,
    float* __restrict__ feat)
{
    const int blk = blockIdx.x;
    const int s = blk >> 2, b = blk & 3;
    const float* wv = (s == 0) ? wq : wans;
    const float bias = (s == 0) ? bq[0] : bans[0];
    const float* lb = lstm + ((size_t)(s * 4 + b)) * LLEN * HD;
    const float* po = proj + ((size_t)((1 - s) * 4 + b)) * LLEN * HD;
    __shared__ float sl[512];
    __shared__ float red[512];
    __shared__ float bcast[2];
    const int tid = threadIdx.x;
    const int wave = tid >> 6, lane = tid & 63;

    const float mb1 = mx[(s * 4 + b) * HD + lane] + ba[lane];
    const float mb2 = mx[(s * 4 + b) * HD + lane + 64] + ba[lane + 64];
    const float wv1a = wv[lane], wv1b = wv[lane + 64];
    const float wv2a = wv[128 + lane], wv2b = wv[192 + lane];

    for (int jj = 0; jj < 64; ++jj) {
        int j = wave + jj * 8;
        float p1 = po[(size_t)j * HD + lane], p2 = po[(size_t)j * HD + lane + 64];
        float r1 = ftanh(mb1 + p1), r2 = ftanh(mb2 + p2);
        float sc = lb[(size_t)j * HD + lane] * wv1a + lb[(size_t)j * HD + lane + 64] * wv1b
                 + r1 * wv2a + r2 * wv2b;
        #pragma unroll
        for (int o = 32; o; o >>= 1) sc += __shfl_down(sc, o, 64);
        if (lane == 0) sl[j] = sc + bias;
    }
    __syncthreads();

    float v = sl[tid];
    float m = v;
    #pragma unroll
    for (int o = 32; o; o >>= 1) m = fmaxf(m, __shfl_xor(m, o, 64));
    if (lane == 0) red[wave] = m;
    __syncthreads();
    if (tid == 0) { float mm = red[0]; for (int i = 1; i < 8; ++i) mm = fmaxf(mm, red[i]); bcast[0] = mm; }
    __syncthreads();
    float e = __expf(v - bcast[0]);
    float ssum = e;
    #pragma unroll
    for (int o = 32; o; o >>= 1) ssum += __shfl_xor(ssum, o, 64);
    if (lane == 0) red[wave] = ssum;
    __syncthreads();
    if (tid == 0) { float tt = 0.f; for (int i = 0; i < 8; ++i) tt += red[i]; bcast[1] = tt; }
    __syncthreads();
    sl[tid] = e / bcast[1];
    __syncthreads();

    const int h = tid & 127, q4 = tid >> 7;
    const float mbh = mx[(s * 4 + b) * HD + h] + ba[h];
    float acc = 0.f;
    for (int jj = 0; jj < 128; ++jj) {
        int j = q4 + jj * 4;
        float r = ftanh(mbh + po[(size_t)j * HD + h]);
        acc += sl[j] * r;
    }
    red[tid] = acc;
    __syncthreads();
    if (tid < 128)
        feat[(s * 4 + b) * HD + tid] = red[tid] + red[128 + tid] + red[256 + tid] + red[384 + tid];
}

// ---------------- K5: final classifier + log_softmax + argmax (fp32 out) ----------------
__global__ void k5_final(const float* __restrict__ feat,
                         const float* __restrict__ wlast, const float* __restrict__ blast,
                         float* __restrict__ outp)
{
    const int tid = threadIdx.x;
    if (tid < 4) {
        const int b = tid;
        float l0 = blast[0], l1 = blast[1];
        for (int k = 0; k < 256; ++k) {
            float f = (k < 128) ? feat[b * HD + k] : feat[(4 + b) * HD + (k - 128)];
            l0 += f * wlast[k * 2 + 0];
            l1 += f * wlast[k * 2 + 1];
        }
        float mxl = fmaxf(l0, l1);
        float lse = mxl + logf(__expf(l0 - mxl) + __expf(l1 - mxl));
        outp[b * 2 + 0] = l0 - lse;
        outp[b * 2 + 1] = l1 - lse;
        outp[8 + b]     = (l1 > l0) ? 1.f : 0.f;
    }
}

extern "C" void kernel_launch(void* const* d_in, const int* in_sizes, int n_in,
                              void* d_out, int out_size, void* d_ws, size_t ws_size,
                              hipStream_t stream)
{
    const int*   qc    = (const int*)d_in[0];
    const int*   ac    = (const int*)d_in[1];
    const float* emb   = (const float*)d_in[2];
    const float* wih   = (const float*)d_in[3];
    const float* whh   = (const float*)d_in[4];
    const float* bl    = (const float*)d_in[5];
    const float* wa    = (const float*)d_in[6];
    const float* ba    = (const float*)d_in[7];
    const float* wq    = (const float*)d_in[8];
    const float* bq    = (const float*)d_in[9];
    const float* wans  = (const float*)d_in[10];
    const float* bans  = (const float*)d_in[11];
    const float* wlast = (const float*)d_in[12];
    const float* blast = (const float*)d_in[13];

    float* ws   = (float*)d_ws;
    float* preg = ws;
    float* lstm = ws + OFF_LSTM;
    float* proj = ws + OFF_PROJ;
    float* mx   = ws + OFF_MX;
    float* feat = ws + OFF_FEAT;

    k1_gemm<<<dim3(64, 8), 256, 0, stream>>>(qc, ac, emb, wih, bl, preg);
    k2_lstm_mfma<<<8, 512, 0, stream>>>(whh, preg, lstm);
    k3_proj<<<32, 512, 0, stream>>>(wa, lstm, proj);
    k3_max<<<8, 512, 0, stream>>>(proj, mx);
    k4_attn<<<8, 512, 0, stream>>>(lstm, proj, mx, ba, wq, bq, wans, bans, feat);
    k5_final<<<1, 64, 0, stream>>>(feat, wlast, blast, (float*)d_out);
}

// Round 7
// 525.145 us; speedup vs baseline: 1.5332x; 1.0493x over previous
//
#include <hip/hip_runtime.h>
#include <hip/hip_bf16.h>

#define EMBED 300
#define HD    128
#define LLEN  512
#define G4    512   // 4*H

// Workspace layout (floats):
#define OFF_LSTM 2097152
#define OFF_PROJ 2621440
#define OFF_MX   3145728
#define OFF_FEAT 3146752

typedef _Float16 half8 __attribute__((ext_vector_type(8)));
typedef float    f32x4 __attribute__((ext_vector_type(4)));

__device__ __forceinline__ float fsig(float x) {
    return __fdividef(1.f, 1.f + __expf(-x));
}
__device__ __forceinline__ float ftanh(float x) {
    return 1.f - __fdividef(2.f, __expf(2.f * x) + 1.f);
}

// ---------------- K1: embedding gather + X @ W_ih + b  → pre_g ----------------
__global__ __launch_bounds__(256) void k1_gemm(
    const int* __restrict__ qc, const int* __restrict__ ac,
    const float* __restrict__ emb, const float* __restrict__ wih,
    const float* __restrict__ bl, float* __restrict__ preg)
{
    __shared__ float As[32][65];
    __shared__ float Bs[32][64];
    const int m0 = blockIdx.x * 64;
    const int n0 = blockIdx.y * 64;
    const int tid = threadIdx.x;
    const int tx = tid & 15, ty = tid >> 4;
    float acc[4][4] = {};

    for (int k0 = 0; k0 < 300; k0 += 32) {
        #pragma unroll
        for (int i = 0; i < 8; ++i) {
            int e = tid + i * 256;
            int m = e >> 5, kk = e & 31;
            int row = m0 + m;
            int c = row >> 11, b = (row >> 9) & 3, t = row & 511;
            int tok = (c == 0 ? qc : ac)[b * LLEN + t];
            int k = k0 + kk;
            As[kk][m] = (k < 300) ? emb[(size_t)tok * EMBED + k] : 0.f;
        }
        #pragma unroll
        for (int i = 0; i < 8; ++i) {
            int e = tid + i * 256;
            int kk = e >> 6, n = e & 63;
            int k = k0 + kk;
            Bs[kk][n] = (k < 300) ? wih[k * G4 + n0 + n] : 0.f;
        }
        __syncthreads();
        #pragma unroll
        for (int kk = 0; kk < 32; ++kk) {
            float a[4], bv[4];
            #pragma unroll
            for (int i = 0; i < 4; ++i) a[i] = As[kk][ty * 4 + i];
            #pragma unroll
            for (int j = 0; j < 4; ++j) bv[j] = Bs[kk][tx * 4 + j];
            #pragma unroll
            for (int i = 0; i < 4; ++i)
                #pragma unroll
                for (int j = 0; j < 4; ++j)
                    acc[i][j] += a[i] * bv[j];
        }
        __syncthreads();
    }
    #pragma unroll
    for (int i = 0; i < 4; ++i) {
        int row = m0 + ty * 4 + i;
        #pragma unroll
        for (int j = 0; j < 4; ++j) {
            int n = n0 + tx * 4 + j;
            preg[(size_t)row * G4 + n] = acc[i][j] + bl[n];
        }
    }
}

// ---------------- K2: MFMA LSTM scan + fused proj/max tail. 8 WGs ----------------
__global__ __launch_bounds__(512, 1) void k2_lstm_mfma(
    const float* __restrict__ whh, const float* __restrict__ preg,
    const float* __restrict__ wa,
    float* __restrict__ lstm, float* __restrict__ proj, float* __restrict__ mx)
{
    const int seq = blockIdx.x;          // c*4 + b, 0..7
    const int tid = threadIdx.x;
    const int w  = tid >> 6;             // wave 0..7
    const int l  = tid & 63;
    const int li = l & 15;
    const int g  = l >> 4;

    __shared__ __align__(16) _Float16 h0[128];
    __shared__ __align__(16) _Float16 h1[128];

    // static A fragments: A[m=li][k=kt*32+g*8+e] = Whh[k][mg], mg = s*128 + w*16 + li
    half8 afrag[4][4];
    #pragma unroll
    for (int s = 0; s < 4; ++s) {
        const int mg = s * 128 + w * 16 + li;
        #pragma unroll
        for (int kt = 0; kt < 4; ++kt) {
            half8 v;
            #pragma unroll
            for (int e = 0; e < 8; ++e)
                v[e] = (_Float16)whh[(kt * 32 + g * 8 + e) * G4 + mg];
            afrag[kt][s] = v;
        }
    }

    if (tid < 128) { h0[tid] = (_Float16)0.f; h1[tid] = (_Float16)0.f; }

    const f32x4* pg4 = (const f32x4*)(preg + (size_t)seq * LLEN * G4);
    const int pgo = w * 4 + g;           // f32x4 idx; + t*128 + s*32
    const int r   = li & 3;
    const int unit = w * 16 + g * 4 + r;
    const bool wlane = li < 4;
    float* outp = lstm + (size_t)seq * LLEN * HD + unit;
    float cst = 0.f;

    f32x4 pgA[4], pgB[4];
    #pragma unroll
    for (int s = 0; s < 4; ++s) pgA[s] = pg4[0 * 128 + s * 32 + pgo];
    #pragma unroll
    for (int s = 0; s < 4; ++s) pgB[s] = pg4[1 * 128 + s * 32 + pgo];

    __syncthreads();

#define LSTM_STEP(T, PGV, RD, WR)                                              \
    {                                                                          \
        half8 bfrag[4];                                                        \
        _Pragma("unroll")                                                      \
        for (int kt = 0; kt < 4; ++kt)                                         \
            bfrag[kt] = *(const half8*)((RD) + kt * 32 + g * 8);               \
        f32x4 a0 = PGV[0], a1 = PGV[1], a2 = PGV[2], a3 = PGV[3];              \
        {                                                                      \
            int tp = (T) + 2; if (tp > 511) tp = 511;                          \
            _Pragma("unroll")                                                  \
            for (int s = 0; s < 4; ++s) PGV[s] = pg4[tp * 128 + s * 32 + pgo]; \
        }                                                                      \
        _Pragma("unroll")                                                      \
        for (int kt = 0; kt < 4; ++kt) {                                       \
            a0 = __builtin_amdgcn_mfma_f32_16x16x32_f16(afrag[kt][0], bfrag[kt], a0, 0, 0, 0); \
            a1 = __builtin_amdgcn_mfma_f32_16x16x32_f16(afrag[kt][1], bfrag[kt], a1, 0, 0, 0); \
            a2 = __builtin_amdgcn_mfma_f32_16x16x32_f16(afrag[kt][2], bfrag[kt], a2, 0, 0, 0); \
            a3 = __builtin_amdgcn_mfma_f32_16x16x32_f16(afrag[kt][3], bfrag[kt], a3, 0, 0, 0); \
        }                                                                      \
        float xi = (r == 0) ? a0[0] : (r == 1) ? a0[1] : (r == 2) ? a0[2] : a0[3]; \
        float xf = (r == 0) ? a1[0] : (r == 1) ? a1[1] : (r == 2) ? a1[2] : a1[3]; \
        float xg = (r == 0) ? a2[0] : (r == 1) ? a2[1] : (r == 2) ? a2[2] : a2[3]; \
        float xo = (r == 0) ? a3[0] : (r == 1) ? a3[1] : (r == 2) ? a3[2] : a3[3]; \
        float i_ = fsig(xi), f_ = fsig(xf), g_ = ftanh(xg), o_ = fsig(xo);     \
        cst = f_ * cst + i_ * g_;                                              \
        float h = o_ * ftanh(cst);                                             \
        if (wlane) {                                                           \
            outp[(size_t)(T) * HD] = h;                                        \
            (WR)[unit] = (_Float16)h;                                          \
        }                                                                      \
        asm volatile("s_waitcnt lgkmcnt(0)" ::: "memory");                     \
        __builtin_amdgcn_sched_barrier(0);                                     \
        __builtin_amdgcn_s_barrier();                                          \
        __builtin_amdgcn_sched_barrier(0);                                     \
    }

    #pragma unroll 1
    for (int tt = 0; tt < 256; ++tt) {
        const int t0 = tt * 2;
        LSTM_STEP(t0,     pgA, h0, h1);
        LSTM_STEP(t0 + 1, pgB, h1, h0);
    }
#undef LSTM_STEP

    // ---- fused proj + max tail: proj[seq] = lstm[seq] @ Wa_side, mx[seq][h] ----
    // Wave w owns h-tile w*16..w*16+15. Same frag maps as the scan (verified).
    __syncthreads();   // drains vmcnt(0): all lstm stores visible to all threads

    {
        const int s_side = seq >> 2;
        half8 bpj[4];
        #pragma unroll
        for (int kt = 0; kt < 4; ++kt) {
            half8 v;
            #pragma unroll
            for (int e = 0; e < 8; ++e)
                v[e] = (_Float16)wa[(s_side * 128 + kt * 32 + g * 8 + e) * 128 + (w * 16 + li)];
            bpj[kt] = v;
        }
        const float* lb = lstm + (size_t)seq * LLEN * HD;
        float* pb = proj + (size_t)seq * LLEN * HD;
        float pmax = -1e30f;
        #pragma unroll 2
        for (int tile = 0; tile < 32; ++tile) {
            const int t0 = tile * 16;
            const float* ar = lb + (size_t)(t0 + li) * HD;
            f32x4 acc = {0.f, 0.f, 0.f, 0.f};
            #pragma unroll
            for (int kt = 0; kt < 4; ++kt) {
                float4 u0 = *(const float4*)(ar + kt * 32 + g * 8);
                float4 u1 = *(const float4*)(ar + kt * 32 + g * 8 + 4);
                half8 a;
                a[0] = (_Float16)u0.x; a[1] = (_Float16)u0.y;
                a[2] = (_Float16)u0.z; a[3] = (_Float16)u0.w;
                a[4] = (_Float16)u1.x; a[5] = (_Float16)u1.y;
                a[6] = (_Float16)u1.z; a[7] = (_Float16)u1.w;
                acc = __builtin_amdgcn_mfma_f32_16x16x32_f16(a, bpj[kt], acc, 0, 0, 0);
            }
            #pragma unroll
            for (int reg = 0; reg < 4; ++reg) {
                pb[(size_t)(t0 + g * 4 + reg) * HD + (w * 16 + li)] = acc[reg];
                pmax = fmaxf(pmax, acc[reg]);
            }
        }
        pmax = fmaxf(pmax, __shfl_xor(pmax, 16, 64));
        pmax = fmaxf(pmax, __shfl_xor(pmax, 32, 64));
        if (g == 0) mx[seq * HD + w * 16 + li] = pmax;
    }
}

// ---------------- K45: both-side attention + final classifier. 4 WGs ----------------
__global__ __launch_bounds__(512) void k45_attn(
    const float* __restrict__ lstm, const float* __restrict__ proj,
    const float* __restrict__ mx, const float* __restrict__ ba,
    const float* __restrict__ wq, const float* __restrict__ bq,
    const float* __restrict__ wans, const float* __restrict__ bans,
    const float* __restrict__ wlast, const float* __restrict__ blast,
    float* __restrict__ outp)
{
    const int b = blockIdx.x;            // 0..3
    __shared__ float sl[512];
    __shared__ float red[512];
    __shared__ float bcast[2];
    __shared__ float feats[2][128];
    const int tid = threadIdx.x;
    const int wave = tid >> 6, lane = tid & 63;

    #pragma unroll 1
    for (int s = 0; s < 2; ++s) {
        const float* wv = (s == 0) ? wq : wans;
        const float bias = (s == 0) ? bq[0] : bans[0];
        const float* lb = lstm + ((size_t)(s * 4 + b)) * LLEN * HD;
        const float* po = proj + ((size_t)((1 - s) * 4 + b)) * LLEN * HD;

        const float mb1 = mx[(s * 4 + b) * HD + lane] + ba[lane];
        const float mb2 = mx[(s * 4 + b) * HD + lane + 64] + ba[lane + 64];
        const float wv1a = wv[lane], wv1b = wv[lane + 64];
        const float wv2a = wv[128 + lane], wv2b = wv[192 + lane];

        for (int jj = 0; jj < 64; ++jj) {
            int j = wave + jj * 8;
            float p1 = po[(size_t)j * HD + lane], p2 = po[(size_t)j * HD + lane + 64];
            float r1 = ftanh(mb1 + p1), r2 = ftanh(mb2 + p2);
            float sc = lb[(size_t)j * HD + lane] * wv1a + lb[(size_t)j * HD + lane + 64] * wv1b
                     + r1 * wv2a + r2 * wv2b;
            #pragma unroll
            for (int o = 32; o; o >>= 1) sc += __shfl_down(sc, o, 64);
            if (lane == 0) sl[j] = sc + bias;
        }
        __syncthreads();

        float v = sl[tid];
        float m = v;
        #pragma unroll
        for (int o = 32; o; o >>= 1) m = fmaxf(m, __shfl_xor(m, o, 64));
        if (lane == 0) red[wave] = m;
        __syncthreads();
        if (tid == 0) { float mm = red[0]; for (int i = 1; i < 8; ++i) mm = fmaxf(mm, red[i]); bcast[0] = mm; }
        __syncthreads();
        float e = __expf(v - bcast[0]);
        float ssum = e;
        #pragma unroll
        for (int o = 32; o; o >>= 1) ssum += __shfl_xor(ssum, o, 64);
        if (lane == 0) red[wave] = ssum;
        __syncthreads();
        if (tid == 0) { float tt = 0.f; for (int i = 0; i < 8; ++i) tt += red[i]; bcast[1] = tt; }
        __syncthreads();
        sl[tid] = e / bcast[1];
        __syncthreads();

        const int h = tid & 127, q4 = tid >> 7;
        const float mbh = mx[(s * 4 + b) * HD + h] + ba[h];
        float acc = 0.f;
        for (int jj = 0; jj < 128; ++jj) {
            int j = q4 + jj * 4;
            float rr = ftanh(mbh + po[(size_t)j * HD + h]);
            acc += sl[j] * rr;
        }
        red[tid] = acc;
        __syncthreads();
        if (tid < 128)
            feats[s][tid] = red[tid] + red[128 + tid] + red[256 + tid] + red[384 + tid];
        __syncthreads();
    }

    // final classifier + log_softmax + argmax for this b
    if (tid < 128) {
        float f0 = feats[0][tid], f1 = feats[1][tid];
        sl[tid]       = f0 * wlast[tid * 2 + 0] + f1 * wlast[(128 + tid) * 2 + 0];
        sl[128 + tid] = f0 * wlast[tid * 2 + 1] + f1 * wlast[(128 + tid) * 2 + 1];
    }
    __syncthreads();
    if (tid < 64) {
        float a0 = sl[tid] + sl[tid + 64];
        float a1 = sl[128 + tid] + sl[192 + tid];
        #pragma unroll
        for (int o = 32; o; o >>= 1) {
            a0 += __shfl_down(a0, o, 64);
            a1 += __shfl_down(a1, o, 64);
        }
        if (tid == 0) {
            float l0 = blast[0] + a0, l1 = blast[1] + a1;
            float mxl = fmaxf(l0, l1);
            float lse = mxl + logf(__expf(l0 - mxl) + __expf(l1 - mxl));
            outp[b * 2 + 0] = l0 - lse;
            outp[b * 2 + 1] = l1 - lse;
            outp[8 + b]     = (l1 > l0) ? 1.f : 0.f;
        }
    }
}

extern "C" void kernel_launch(void* const* d_in, const int* in_sizes, int n_in,
                              void* d_out, int out_size, void* d_ws, size_t ws_size,
                              hipStream_t stream)
{
    const int*   qc    = (const int*)d_in[0];
    const int*   ac    = (const int*)d_in[1];
    const float* emb   = (const float*)d_in[2];
    const float* wih   = (const float*)d_in[3];
    const float* whh   = (const float*)d_in[4];
    const float* bl    = (const float*)d_in[5];
    const float* wa    = (const float*)d_in[6];
    const float* ba    = (const float*)d_in[7];
    const float* wq    = (const float*)d_in[8];
    const float* bq    = (const float*)d_in[9];
    const float* wans  = (const float*)d_in[10];
    const float* bans  = (const float*)d_in[11];
    const float* wlast = (const float*)d_in[12];
    const float* blast = (const float*)d_in[13];

    float* ws   = (float*)d_ws;
    float* preg = ws;
    float* lstm = ws + OFF_LSTM;
    float* proj = ws + OFF_PROJ;
    float* mx   = ws + OFF_MX;

    k1_gemm<<<dim3(64, 8), 256, 0, stream>>>(qc, ac, emb, wih, bl, preg);
    k2_lstm_mfma<<<8, 512, 0, stream>>>(whh, preg, wa, lstm, proj, mx);
    k45_attn<<<4, 512, 0, stream>>>(lstm, proj, mx, ba, wq, bq, wans, bans,
                                    wlast, blast, (float*)d_out);
}

// Round 8
// 438.236 us; speedup vs baseline: 1.8373x; 1.1983x over previous
//
#include <hip/hip_runtime.h>
#include <hip/hip_bf16.h>

#define EMBED 300
#define HD    128
#define LLEN  512
#define G4    512   // 4*H

// Workspace layout (floats):
#define OFF_LSTM 2097152
#define OFF_PROJ 2621440
#define OFF_MX   3145728

typedef _Float16 half8 __attribute__((ext_vector_type(8)));
typedef float    f32x4 __attribute__((ext_vector_type(4)));

__device__ __forceinline__ float fsig(float x) {
    return __fdividef(1.f, 1.f + __expf(-x));
}
__device__ __forceinline__ float ftanh(float x) {
    return 1.f - __fdividef(2.f, __expf(2.f * x) + 1.f);
}

// ---------------- K1: embedding gather + X @ W_ih + b  → pre_g ----------------
__global__ __launch_bounds__(256) void k1_gemm(
    const int* __restrict__ qc, const int* __restrict__ ac,
    const float* __restrict__ emb, const float* __restrict__ wih,
    const float* __restrict__ bl, float* __restrict__ preg)
{
    __shared__ float As[32][65];
    __shared__ float Bs[32][64];
    const int m0 = blockIdx.x * 64;
    const int n0 = blockIdx.y * 64;
    const int tid = threadIdx.x;
    const int tx = tid & 15, ty = tid >> 4;
    float acc[4][4] = {};

    for (int k0 = 0; k0 < 300; k0 += 32) {
        #pragma unroll
        for (int i = 0; i < 8; ++i) {
            int e = tid + i * 256;
            int m = e >> 5, kk = e & 31;
            int row = m0 + m;
            int c = row >> 11, b = (row >> 9) & 3, t = row & 511;
            int tok = (c == 0 ? qc : ac)[b * LLEN + t];
            int k = k0 + kk;
            As[kk][m] = (k < 300) ? emb[(size_t)tok * EMBED + k] : 0.f;
        }
        #pragma unroll
        for (int i = 0; i < 8; ++i) {
            int e = tid + i * 256;
            int kk = e >> 6, n = e & 63;
            int k = k0 + kk;
            Bs[kk][n] = (k < 300) ? wih[k * G4 + n0 + n] : 0.f;
        }
        __syncthreads();
        #pragma unroll
        for (int kk = 0; kk < 32; ++kk) {
            float a[4], bv[4];
            #pragma unroll
            for (int i = 0; i < 4; ++i) a[i] = As[kk][ty * 4 + i];
            #pragma unroll
            for (int j = 0; j < 4; ++j) bv[j] = Bs[kk][tx * 4 + j];
            #pragma unroll
            for (int i = 0; i < 4; ++i)
                #pragma unroll
                for (int j = 0; j < 4; ++j)
                    acc[i][j] += a[i] * bv[j];
        }
        __syncthreads();
    }
    #pragma unroll
    for (int i = 0; i < 4; ++i) {
        int row = m0 + ty * 4 + i;
        #pragma unroll
        for (int j = 0; j < 4; ++j) {
            int n = n0 + tx * 4 + j;
            preg[(size_t)row * G4 + n] = acc[i][j] + bl[n];
        }
    }
}

// ---------------- K2: MFMA LSTM scan with in-step proj+max. 8 WGs ----------------
// Gates: D = Whh^T(512x128) @ h (broadcast cols). Proj: D = Wa_side^T(128x128) @ h
// using the SAME bfrag — +4 MFMA/step, zero extra loads. proj[t-1] written at step t.
__global__ __launch_bounds__(512, 1) void k2_lstm_mfma(
    const float* __restrict__ whh, const float* __restrict__ preg,
    const float* __restrict__ wa,
    float* __restrict__ lstm, float* __restrict__ proj, float* __restrict__ mx)
{
    const int seq = blockIdx.x;          // c*4 + b, 0..7
    const int tid = threadIdx.x;
    const int w  = tid >> 6;             // wave 0..7
    const int l  = tid & 63;
    const int li = l & 15;
    const int g  = l >> 4;

    __shared__ __align__(16) _Float16 h0[128];
    __shared__ __align__(16) _Float16 h1[128];

    // static gate A fragments: A[m=li][k=kt*32+g*8+e] = Whh[k][mg], mg = s*128+w*16+li
    half8 afrag[4][4];
    #pragma unroll
    for (int s = 0; s < 4; ++s) {
        const int mg = s * 128 + w * 16 + li;
        #pragma unroll
        for (int kt = 0; kt < 4; ++kt) {
            half8 v;
            #pragma unroll
            for (int e = 0; e < 8; ++e)
                v[e] = (_Float16)whh[(kt * 32 + g * 8 + e) * G4 + mg];
            afrag[kt][s] = v;
        }
    }
    // static proj A fragments: A[m=li][k] = Wa[s_side*128 + k][w*16+li]
    const int s_side = seq >> 2;
    half8 afragW[4];
    #pragma unroll
    for (int kt = 0; kt < 4; ++kt) {
        half8 v;
        #pragma unroll
        for (int e = 0; e < 8; ++e)
            v[e] = (_Float16)wa[(s_side * 128 + kt * 32 + g * 8 + e) * 128 + (w * 16 + li)];
        afragW[kt] = v;
    }

    if (tid < 128) { h0[tid] = (_Float16)0.f; h1[tid] = (_Float16)0.f; }

    const f32x4* pg4 = (const f32x4*)(preg + (size_t)seq * LLEN * G4);
    const int pgo = w * 4 + g;           // f32x4 idx; + t*128 + s*32
    const int r   = li & 3;
    const int unit = w * 16 + g * 4 + r;
    const bool wlane = li < 4;
    float* outp = lstm + (size_t)seq * LLEN * HD + unit;
    float* prp  = proj + (size_t)seq * LLEN * HD + unit;
    float cst = 0.f;
    float pm = -1e30f;

    f32x4 pgA[4], pgB[4];
    #pragma unroll
    for (int s = 0; s < 4; ++s) pgA[s] = pg4[0 * 128 + s * 32 + pgo];
    #pragma unroll
    for (int s = 0; s < 4; ++s) pgB[s] = pg4[1 * 128 + s * 32 + pgo];

    __syncthreads();

#define LSTM_STEP(T, PGV, RD, WR)                                              \
    {                                                                          \
        half8 bfrag[4];                                                        \
        _Pragma("unroll")                                                      \
        for (int kt = 0; kt < 4; ++kt)                                         \
            bfrag[kt] = *(const half8*)((RD) + kt * 32 + g * 8);               \
        f32x4 a0 = PGV[0], a1 = PGV[1], a2 = PGV[2], a3 = PGV[3];              \
        {                                                                      \
            int tp = (T) + 2; if (tp > 511) tp = 511;                          \
            _Pragma("unroll")                                                  \
            for (int s = 0; s < 4; ++s) PGV[s] = pg4[tp * 128 + s * 32 + pgo]; \
        }                                                                      \
        _Pragma("unroll")                                                      \
        for (int kt = 0; kt < 4; ++kt) {                                       \
            a0 = __builtin_amdgcn_mfma_f32_16x16x32_f16(afrag[kt][0], bfrag[kt], a0, 0, 0, 0); \
            a1 = __builtin_amdgcn_mfma_f32_16x16x32_f16(afrag[kt][1], bfrag[kt], a1, 0, 0, 0); \
            a2 = __builtin_amdgcn_mfma_f32_16x16x32_f16(afrag[kt][2], bfrag[kt], a2, 0, 0, 0); \
            a3 = __builtin_amdgcn_mfma_f32_16x16x32_f16(afrag[kt][3], bfrag[kt], a3, 0, 0, 0); \
        }                                                                      \
        f32x4 ap = {0.f, 0.f, 0.f, 0.f};                                       \
        _Pragma("unroll")                                                      \
        for (int kt = 0; kt < 4; ++kt)                                         \
            ap = __builtin_amdgcn_mfma_f32_16x16x32_f16(afragW[kt], bfrag[kt], ap, 0, 0, 0); \
        float xi = (r == 0) ? a0[0] : (r == 1) ? a0[1] : (r == 2) ? a0[2] : a0[3]; \
        float xf = (r == 0) ? a1[0] : (r == 1) ? a1[1] : (r == 2) ? a1[2] : a1[3]; \
        float xg = (r == 0) ? a2[0] : (r == 1) ? a2[1] : (r == 2) ? a2[2] : a2[3]; \
        float xo = (r == 0) ? a3[0] : (r == 1) ? a3[1] : (r == 2) ? a3[2] : a3[3]; \
        float ps = (r == 0) ? ap[0] : (r == 1) ? ap[1] : (r == 2) ? ap[2] : ap[3]; \
        pm = fmaxf(pm, ps);                                                    \
        float i_ = fsig(xi), f_ = fsig(xf), g_ = ftanh(xg), o_ = fsig(xo);     \
        cst = f_ * cst + i_ * g_;                                              \
        float h = o_ * ftanh(cst);                                             \
        if (wlane) {                                                           \
            outp[(size_t)(T) * HD] = h;                                        \
            if ((T) > 0) prp[(size_t)((T) - 1) * HD] = ps;                     \
            (WR)[unit] = (_Float16)h;                                          \
        }                                                                      \
        asm volatile("s_waitcnt lgkmcnt(0)" ::: "memory");                     \
        __builtin_amdgcn_sched_barrier(0);                                     \
        __builtin_amdgcn_s_barrier();                                          \
        __builtin_amdgcn_sched_barrier(0);                                     \
    }

    #pragma unroll 1
    for (int tt = 0; tt < 256; ++tt) {
        const int t0 = tt * 2;
        LSTM_STEP(t0,     pgA, h0, h1);
        LSTM_STEP(t0 + 1, pgB, h1, h0);
    }
#undef LSTM_STEP

    // epilogue: proj[511] from h_511 (in h0 after final step) + mx store
    {
        half8 bfin[4];
        #pragma unroll
        for (int kt = 0; kt < 4; ++kt)
            bfin[kt] = *(const half8*)(h0 + kt * 32 + g * 8);
        f32x4 ap = {0.f, 0.f, 0.f, 0.f};
        #pragma unroll
        for (int kt = 0; kt < 4; ++kt)
            ap = __builtin_amdgcn_mfma_f32_16x16x32_f16(afragW[kt], bfin[kt], ap, 0, 0, 0);
        float ps = (r == 0) ? ap[0] : (r == 1) ? ap[1] : (r == 2) ? ap[2] : ap[3];
        pm = fmaxf(pm, ps);
        if (wlane) {
            prp[(size_t)511 * HD] = ps;
            mx[seq * HD + unit] = pm;
        }
    }
}

// ---------------- K45: one-pass attention (both sides parallel) + classifier. 4 WGs ----------------
// softmax shift-invariance: feature = (Σ e^{sc_j} r_j) / (Σ e^{sc_j}); |sc| <= 16 so e^sc fp32-safe.
__global__ __launch_bounds__(512) void k45_attn(
    const float* __restrict__ lstm, const float* __restrict__ proj,
    const float* __restrict__ mx, const float* __restrict__ ba,
    const float* __restrict__ wq, const float* __restrict__ wans,
    const float* __restrict__ wlast, const float* __restrict__ blast,
    float* __restrict__ outp)
{
    const int b = blockIdx.x;            // 0..3
    const int tid = threadIdx.x;
    const int wave = tid >> 6, lane = tid & 63;
    const int s = wave >> 2;             // side: waves 0-3 -> q, 4-7 -> a
    const int ws = wave & 3;

    __shared__ float nred[8][128];
    __shared__ float dred[8];
    __shared__ float feats[2][128];
    __shared__ float cls[256];

    const float* wv = (s == 0) ? wq : wans;
    const float* lb = lstm + ((size_t)(s * 4 + b)) * LLEN * HD;
    const float* po = proj + ((size_t)((1 - s) * 4 + b)) * LLEN * HD;

    const float mb1 = mx[(s * 4 + b) * HD + lane] + ba[lane];
    const float mb2 = mx[(s * 4 + b) * HD + lane + 64] + ba[lane + 64];
    const float wv1a = wv[lane], wv1b = wv[lane + 64];
    const float wv2a = wv[128 + lane], wv2b = wv[192 + lane];

    float n1 = 0.f, n2 = 0.f, den = 0.f;
    #pragma unroll 4
    for (int jj = 0; jj < 128; ++jj) {
        const int j = ws + jj * 4;
        float L1 = lb[(size_t)j * HD + lane];
        float L2 = lb[(size_t)j * HD + lane + 64];
        float P1 = po[(size_t)j * HD + lane];
        float P2 = po[(size_t)j * HD + lane + 64];
        float r1 = ftanh(mb1 + P1), r2 = ftanh(mb2 + P2);
        float sc = L1 * wv1a + L2 * wv1b + r1 * wv2a + r2 * wv2b;
        #pragma unroll
        for (int o = 32; o; o >>= 1) sc += __shfl_xor(sc, o, 64);
        float e = __expf(sc);
        den += e;
        n1 += e * r1;
        n2 += e * r2;
    }
    nred[wave][lane] = n1;
    nred[wave][lane + 64] = n2;
    if (lane == 0) dred[wave] = den;
    __syncthreads();

    if (tid < 256) {
        const int ss = tid >> 7, h = tid & 127;
        float num = nred[ss * 4 + 0][h] + nred[ss * 4 + 1][h]
                  + nred[ss * 4 + 2][h] + nred[ss * 4 + 3][h];
        float dd  = dred[ss * 4 + 0] + dred[ss * 4 + 1]
                  + dred[ss * 4 + 2] + dred[ss * 4 + 3];
        feats[ss][h] = num / dd;
    }
    __syncthreads();

    if (tid < 128) {
        float f0 = feats[0][tid], f1 = feats[1][tid];
        cls[tid]       = f0 * wlast[tid * 2 + 0] + f1 * wlast[(128 + tid) * 2 + 0];
        cls[128 + tid] = f0 * wlast[tid * 2 + 1] + f1 * wlast[(128 + tid) * 2 + 1];
    }
    __syncthreads();
    if (tid < 64) {
        float a0 = cls[tid] + cls[tid + 64];
        float a1 = cls[128 + tid] + cls[192 + tid];
        #pragma unroll
        for (int o = 32; o; o >>= 1) {
            a0 += __shfl_down(a0, o, 64);
            a1 += __shfl_down(a1, o, 64);
        }
        if (tid == 0) {
            float l0 = blast[0] + a0, l1 = blast[1] + a1;
            float mxl = fmaxf(l0, l1);
            float lse = mxl + logf(__expf(l0 - mxl) + __expf(l1 - mxl));
            outp[b * 2 + 0] = l0 - lse;
            outp[b * 2 + 1] = l1 - lse;
            outp[8 + b]     = (l1 > l0) ? 1.f : 0.f;
        }
    }
}

extern "C" void kernel_launch(void* const* d_in, const int* in_sizes, int n_in,
                              void* d_out, int out_size, void* d_ws, size_t ws_size,
                              hipStream_t stream)
{
    const int*   qc    = (const int*)d_in[0];
    const int*   ac    = (const int*)d_in[1];
    const float* emb   = (const float*)d_in[2];
    const float* wih   = (const float*)d_in[3];
    const float* whh   = (const float*)d_in[4];
    const float* bl    = (const float*)d_in[5];
    const float* wa    = (const float*)d_in[6];
    const float* ba    = (const float*)d_in[7];
    const float* wq    = (const float*)d_in[8];
    const float* wans  = (const float*)d_in[10];
    const float* wlast = (const float*)d_in[12];
    const float* blast = (const float*)d_in[13];

    float* ws   = (float*)d_ws;
    float* preg = ws;
    float* lstm = ws + OFF_LSTM;
    float* proj = ws + OFF_PROJ;
    float* mx   = ws + OFF_MX;

    k1_gemm<<<dim3(64, 8), 256, 0, stream>>>(qc, ac, emb, wih, bl, preg);
    k2_lstm_mfma<<<8, 512, 0, stream>>>(whh, preg, wa, lstm, proj, mx);
    k45_attn<<<4, 512, 0, stream>>>(lstm, proj, mx, ba, wq, wans,
                                    wlast, blast, (float*)d_out);
}

// Round 9
// 389.910 us; speedup vs baseline: 2.0650x; 1.1239x over previous
//
#include <hip/hip_runtime.h>
#include <hip/hip_bf16.h>

#define EMBED 300
#define HD    128
#define LLEN  512
#define G4    512   // 4*H

// Workspace layout (floats):
// preg [2][4][512][512] @0 (dead after k2; k45a partials reuse it)
#define OFF_LSTM 2097152
#define OFF_PROJ 2621440
#define OFF_MX   3145728

typedef _Float16 half8 __attribute__((ext_vector_type(8)));
typedef float    f32x4 __attribute__((ext_vector_type(4)));

__device__ __forceinline__ float fsig(float x) {
    return __fdividef(1.f, 1.f + __expf(-x));
}
__device__ __forceinline__ float ftanh(float x) {
    return 1.f - __fdividef(2.f, __expf(2.f * x) + 1.f);
}

// ---------------- K1: embedding gather + X @ W_ih + b  → pre_g ----------------
__global__ __launch_bounds__(256) void k1_gemm(
    const int* __restrict__ qc, const int* __restrict__ ac,
    const float* __restrict__ emb, const float* __restrict__ wih,
    const float* __restrict__ bl, float* __restrict__ preg)
{
    __shared__ float As[32][65];
    __shared__ float Bs[32][64];
    const int m0 = blockIdx.x * 64;
    const int n0 = blockIdx.y * 64;
    const int tid = threadIdx.x;
    const int tx = tid & 15, ty = tid >> 4;
    float acc[4][4] = {};

    for (int k0 = 0; k0 < 300; k0 += 32) {
        #pragma unroll
        for (int i = 0; i < 8; ++i) {
            int e = tid + i * 256;
            int m = e >> 5, kk = e & 31;
            int row = m0 + m;
            int c = row >> 11, b = (row >> 9) & 3, t = row & 511;
            int tok = (c == 0 ? qc : ac)[b * LLEN + t];
            int k = k0 + kk;
            As[kk][m] = (k < 300) ? emb[(size_t)tok * EMBED + k] : 0.f;
        }
        #pragma unroll
        for (int i = 0; i < 8; ++i) {
            int e = tid + i * 256;
            int kk = e >> 6, n = e & 63;
            int k = k0 + kk;
            Bs[kk][n] = (k < 300) ? wih[k * G4 + n0 + n] : 0.f;
        }
        __syncthreads();
        #pragma unroll
        for (int kk = 0; kk < 32; ++kk) {
            float a[4], bv[4];
            #pragma unroll
            for (int i = 0; i < 4; ++i) a[i] = As[kk][ty * 4 + i];
            #pragma unroll
            for (int j = 0; j < 4; ++j) bv[j] = Bs[kk][tx * 4 + j];
            #pragma unroll
            for (int i = 0; i < 4; ++i)
                #pragma unroll
                for (int j = 0; j < 4; ++j)
                    acc[i][j] += a[i] * bv[j];
        }
        __syncthreads();
    }
    #pragma unroll
    for (int i = 0; i < 4; ++i) {
        int row = m0 + ty * 4 + i;
        #pragma unroll
        for (int j = 0; j < 4; ++j) {
            int n = n0 + tx * 4 + j;
            preg[(size_t)row * G4 + n] = acc[i][j] + bl[n];
        }
    }
}

// ---------------- K2: MFMA LSTM scan + 16-step-batched proj. 8 WGs ----------------
// h history ring: 32 slots (2 windows of 16). Step t reads slot (t-1)&31, writes t&31.
// Every 16 steps: proj GEMM where B-columns = 16 time slots (no N-waste), 4 MFMA/wave.
__global__ __launch_bounds__(512, 1) void k2_lstm_mfma(
    const float* __restrict__ whh, const float* __restrict__ preg,
    const float* __restrict__ wa,
    float* __restrict__ lstm, float* __restrict__ proj, float* __restrict__ mx)
{
    const int seq = blockIdx.x;          // c*4 + b, 0..7
    const int tid = threadIdx.x;
    const int w  = tid >> 6;             // wave 0..7
    const int l  = tid & 63;
    const int li = l & 15;
    const int g  = l >> 4;

    __shared__ __align__(16) _Float16 hist[32 * 136];   // padded rows (272B, 16B-mult)

    // static gate A fragments: A[m=li][k=kt*32+g*8+e] = Whh[k][mg], mg = s*128+w*16+li
    half8 afrag[4][4];
    #pragma unroll
    for (int s = 0; s < 4; ++s) {
        const int mg = s * 128 + w * 16 + li;
        #pragma unroll
        for (int kt = 0; kt < 4; ++kt) {
            half8 v;
            #pragma unroll
            for (int e = 0; e < 8; ++e)
                v[e] = (_Float16)whh[(kt * 32 + g * 8 + e) * G4 + mg];
            afrag[kt][s] = v;
        }
    }
    // static proj A fragments: A[m=li][k] = Wa[s_side*128 + k][w*16+li]
    const int s_side = seq >> 2;
    half8 afragW[4];
    #pragma unroll
    for (int kt = 0; kt < 4; ++kt) {
        half8 v;
        #pragma unroll
        for (int e = 0; e < 8; ++e)
            v[e] = (_Float16)wa[(s_side * 128 + kt * 32 + g * 8 + e) * 128 + (w * 16 + li)];
        afragW[kt] = v;
    }

    for (int i = tid; i < 32 * 68; i += 512) ((unsigned*)hist)[i] = 0u;

    const f32x4* pg4 = (const f32x4*)(preg + (size_t)seq * LLEN * G4);
    const int pgo = w * 4 + g;           // f32x4 idx; + t*128 + s*32
    const int r   = li & 3;
    const int unit = w * 16 + g * 4 + r;
    const bool wlane = li < 4;
    float* outp = lstm + (size_t)seq * LLEN * HD + unit;
    float cst = 0.f;
    float pmr0 = -1e30f, pmr1 = -1e30f, pmr2 = -1e30f, pmr3 = -1e30f;

    f32x4 pgA[4], pgB[4];
    #pragma unroll
    for (int s = 0; s < 4; ++s) pgA[s] = pg4[0 * 128 + s * 32 + pgo];
    #pragma unroll
    for (int s = 0; s < 4; ++s) pgB[s] = pg4[1 * 128 + s * 32 + pgo];

    __syncthreads();

#define LSTM_STEP(T, PGV, RD, WR)                                              \
    {                                                                          \
        half8 bfrag[4];                                                        \
        _Pragma("unroll")                                                      \
        for (int kt = 0; kt < 4; ++kt)                                         \
            bfrag[kt] = *(const half8*)((RD) + kt * 32 + g * 8);               \
        f32x4 a0 = PGV[0], a1 = PGV[1], a2 = PGV[2], a3 = PGV[3];              \
        {                                                                      \
            int tp = (T) + 2; if (tp > 511) tp = 511;                          \
            _Pragma("unroll")                                                  \
            for (int s = 0; s < 4; ++s) PGV[s] = pg4[tp * 128 + s * 32 + pgo]; \
        }                                                                      \
        _Pragma("unroll")                                                      \
        for (int kt = 0; kt < 4; ++kt) {                                       \
            a0 = __builtin_amdgcn_mfma_f32_16x16x32_f16(afrag[kt][0], bfrag[kt], a0, 0, 0, 0); \
            a1 = __builtin_amdgcn_mfma_f32_16x16x32_f16(afrag[kt][1], bfrag[kt], a1, 0, 0, 0); \
            a2 = __builtin_amdgcn_mfma_f32_16x16x32_f16(afrag[kt][2], bfrag[kt], a2, 0, 0, 0); \
            a3 = __builtin_amdgcn_mfma_f32_16x16x32_f16(afrag[kt][3], bfrag[kt], a3, 0, 0, 0); \
        }                                                                      \
        float xi = (r == 0) ? a0[0] : (r == 1) ? a0[1] : (r == 2) ? a0[2] : a0[3]; \
        float xf = (r == 0) ? a1[0] : (r == 1) ? a1[1] : (r == 2) ? a1[2] : a1[3]; \
        float xg = (r == 0) ? a2[0] : (r == 1) ? a2[1] : (r == 2) ? a2[2] : a2[3]; \
        float xo = (r == 0) ? a3[0] : (r == 1) ? a3[1] : (r == 2) ? a3[2] : a3[3]; \
        float i_ = fsig(xi), f_ = fsig(xf), g_ = ftanh(xg), o_ = fsig(xo);     \
        cst = f_ * cst + i_ * g_;                                              \
        float h = o_ * ftanh(cst);                                             \
        if (wlane) {                                                           \
            outp[(size_t)(T) * HD] = h;                                        \
            (WR)[unit] = (_Float16)h;                                          \
        }                                                                      \
        asm volatile("s_waitcnt lgkmcnt(0)" ::: "memory");                     \
        __builtin_amdgcn_sched_barrier(0);                                     \
        __builtin_amdgcn_s_barrier();                                          \
        __builtin_amdgcn_sched_barrier(0);                                     \
    }

    #pragma unroll 1
    for (int tt = 0; tt < 256; ++tt) {
        const int t0 = tt * 2;
        const int slot = t0 & 31;
        _Float16* wr0 = hist + slot * 136;
        const _Float16* rd0 = hist + ((slot + 31) & 31) * 136;
        _Float16* wr1 = hist + (slot + 1) * 136;
        LSTM_STEP(t0,     pgA, rd0, wr0);
        LSTM_STEP(t0 + 1, pgB, wr0, wr1);
        if ((tt & 7) == 7) {
            // batched proj for the window just completed: slots p*16..p*16+15
            // = h_{tbase}..h_{tbase+15}; next 16 steps write the OTHER window.
            const int p = (tt >> 3) & 1;
            const int tbase = t0 - 14;
            const _Float16* hb = hist + (p * 16 + li) * 136;
            half8 bb0 = *(const half8*)(hb + 0 * 32 + g * 8);
            half8 bb1 = *(const half8*)(hb + 1 * 32 + g * 8);
            half8 bb2 = *(const half8*)(hb + 2 * 32 + g * 8);
            half8 bb3 = *(const half8*)(hb + 3 * 32 + g * 8);
            f32x4 pa = {0.f, 0.f, 0.f, 0.f};
            pa = __builtin_amdgcn_mfma_f32_16x16x32_f16(afragW[0], bb0, pa, 0, 0, 0);
            pa = __builtin_amdgcn_mfma_f32_16x16x32_f16(afragW[1], bb1, pa, 0, 0, 0);
            pa = __builtin_amdgcn_mfma_f32_16x16x32_f16(afragW[2], bb2, pa, 0, 0, 0);
            pa = __builtin_amdgcn_mfma_f32_16x16x32_f16(afragW[3], bb3, pa, 0, 0, 0);
            // D[row=g*4+reg][col=li=time]: store proj[seq][tbase+li][w*16+g*4+reg]
            float* pp = proj + (size_t)seq * LLEN * HD
                      + (size_t)(tbase + li) * HD + w * 16 + g * 4;
            *(f32x4*)pp = pa;
            pmr0 = fmaxf(pmr0, pa[0]);
            pmr1 = fmaxf(pmr1, pa[1]);
            pmr2 = fmaxf(pmr2, pa[2]);
            pmr3 = fmaxf(pmr3, pa[3]);
        }
    }
#undef LSTM_STEP

    // mx: reduce running max over the 16 li lanes (time slices), store per row
    #pragma unroll
    for (int m = 1; m <= 8; m <<= 1) {
        pmr0 = fmaxf(pmr0, __shfl_xor(pmr0, m, 64));
        pmr1 = fmaxf(pmr1, __shfl_xor(pmr1, m, 64));
        pmr2 = fmaxf(pmr2, __shfl_xor(pmr2, m, 64));
        pmr3 = fmaxf(pmr3, __shfl_xor(pmr3, m, 64));
    }
    if (li == 0) {
        mx[seq * HD + w * 16 + g * 4 + 0] = pmr0;
        mx[seq * HD + w * 16 + g * 4 + 1] = pmr1;
        mx[seq * HD + w * 16 + g * 4 + 2] = pmr2;
        mx[seq * HD + w * 16 + g * 4 + 3] = pmr3;
    }
}

// ---------------- K45a: partial one-pass attention. 32 WGs ----------------
__global__ __launch_bounds__(512) void k45a_attn(
    const float* __restrict__ lstm, const float* __restrict__ proj,
    const float* __restrict__ mx, const float* __restrict__ ba,
    const float* __restrict__ wq, const float* __restrict__ wans,
    float* __restrict__ pn, float* __restrict__ pd)
{
    const int bid = blockIdx.x;          // 0..31
    const int chunk = bid & 3, sb = bid >> 2;
    const int s = sb >> 2, b = sb & 3;
    const int tid = threadIdx.x;
    const int wave = tid >> 6, lane = tid & 63;

    __shared__ float nred[8][128];
    __shared__ float dred[8];

    const float* wv = (s == 0) ? wq : wans;
    const float* lb = lstm + (size_t)sb * LLEN * HD;
    const float* po = proj + (size_t)((1 - s) * 4 + b) * LLEN * HD;

    const float mb1 = mx[sb * HD + lane] + ba[lane];
    const float mb2 = mx[sb * HD + lane + 64] + ba[lane + 64];
    const float wv1a = wv[lane], wv1b = wv[lane + 64];
    const float wv2a = wv[128 + lane], wv2b = wv[192 + lane];

    float n1 = 0.f, n2 = 0.f, den = 0.f;
    #pragma unroll 4
    for (int jj = 0; jj < 16; ++jj) {
        const int j = chunk * 128 + wave + jj * 8;
        float L1 = lb[(size_t)j * HD + lane];
        float L2 = lb[(size_t)j * HD + lane + 64];
        float P1 = po[(size_t)j * HD + lane];
        float P2 = po[(size_t)j * HD + lane + 64];
        float r1 = ftanh(mb1 + P1), r2 = ftanh(mb2 + P2);
        float sc = L1 * wv1a + L2 * wv1b + r1 * wv2a + r2 * wv2b;
        #pragma unroll
        for (int o = 32; o; o >>= 1) sc += __shfl_xor(sc, o, 64);
        float e = __expf(sc);
        den += e;
        n1 += e * r1;
        n2 += e * r2;
    }
    nred[wave][lane] = n1;
    nred[wave][lane + 64] = n2;
    if (lane == 0) dred[wave] = den;
    __syncthreads();

    if (tid < 128) {
        float s8 = 0.f;
        #pragma unroll
        for (int i = 0; i < 8; ++i) s8 += nred[i][tid];
        pn[bid * 128 + tid] = s8;
    }
    if (tid == 128) {
        float dd = 0.f;
        #pragma unroll
        for (int i = 0; i < 8; ++i) dd += dred[i];
        pd[bid] = dd;
    }
}

// ---------------- K45b: merge partials + classifier + log_softmax. 4 WGs ----------------
__global__ __launch_bounds__(256) void k45b_final(
    const float* __restrict__ pn, const float* __restrict__ pd,
    const float* __restrict__ wlast, const float* __restrict__ blast,
    float* __restrict__ outp)
{
    const int b = blockIdx.x;            // 0..3
    const int tid = threadIdx.x;
    __shared__ float feats[2][128];
    __shared__ float cls[256];

    {
        const int ss = tid >> 7, h = tid & 127;
        const int base = (ss * 4 + b) * 4;
        float num = pn[(base + 0) * 128 + h] + pn[(base + 1) * 128 + h]
                  + pn[(base + 2) * 128 + h] + pn[(base + 3) * 128 + h];
        float dd  = pd[base + 0] + pd[base + 1] + pd[base + 2] + pd[base + 3];
        feats[ss][h] = num / dd;
    }
    __syncthreads();

    if (tid < 128) {
        float f0 = feats[0][tid], f1 = feats[1][tid];
        cls[tid]       = f0 * wlast[tid * 2 + 0] + f1 * wlast[(128 + tid) * 2 + 0];
        cls[128 + tid] = f0 * wlast[tid * 2 + 1] + f1 * wlast[(128 + tid) * 2 + 1];
    }
    __syncthreads();
    if (tid < 64) {
        float a0 = cls[tid] + cls[tid + 64];
        float a1 = cls[128 + tid] + cls[192 + tid];
        #pragma unroll
        for (int o = 32; o; o >>= 1) {
            a0 += __shfl_down(a0, o, 64);
            a1 += __shfl_down(a1, o, 64);
        }
        if (tid == 0) {
            float l0 = blast[0] + a0, l1 = blast[1] + a1;
            float mxl = fmaxf(l0, l1);
            float lse = mxl + logf(__expf(l0 - mxl) + __expf(l1 - mxl));
            outp[b * 2 + 0] = l0 - lse;
            outp[b * 2 + 1] = l1 - lse;
            outp[8 + b]     = (l1 > l0) ? 1.f : 0.f;
        }
    }
}

extern "C" void kernel_launch(void* const* d_in, const int* in_sizes, int n_in,
                              void* d_out, int out_size, void* d_ws, size_t ws_size,
                              hipStream_t stream)
{
    const int*   qc    = (const int*)d_in[0];
    const int*   ac    = (const int*)d_in[1];
    const float* emb   = (const float*)d_in[2];
    const float* wih   = (const float*)d_in[3];
    const float* whh   = (const float*)d_in[4];
    const float* bl    = (const float*)d_in[5];
    const float* wa    = (const float*)d_in[6];
    const float* ba    = (const float*)d_in[7];
    const float* wq    = (const float*)d_in[8];
    const float* wans  = (const float*)d_in[10];
    const float* wlast = (const float*)d_in[12];
    const float* blast = (const float*)d_in[13];

    float* ws   = (float*)d_ws;
    float* preg = ws;
    float* lstm = ws + OFF_LSTM;
    float* proj = ws + OFF_PROJ;
    float* mx   = ws + OFF_MX;
    float* pn   = ws;          // preg region is dead after k2
    float* pd   = ws + 4096;

    k1_gemm<<<dim3(64, 8), 256, 0, stream>>>(qc, ac, emb, wih, bl, preg);
    k2_lstm_mfma<<<8, 512, 0, stream>>>(whh, preg, wa, lstm, proj, mx);
    k45a_attn<<<32, 512, 0, stream>>>(lstm, proj, mx, ba, wq, wans, pn, pd);
    k45b_final<<<4, 256, 0, stream>>>(pn, pd, wlast, blast, (float*)d_out);
}